// Round 8
// baseline (999.718 us; speedup 1.0000x reference)
//
#include <hip/hip_runtime.h>

#define D 64

__device__ __forceinline__ float relu_f(float v) { return v > 0.f ? v : 0.f; }

// ---------------- CSR build: histogram + 3-pass scan + permute ----------------

__global__ void k_hist(const int* __restrict__ ac, int* __restrict__ cnt, int T) {
    int t = blockIdx.x * blockDim.x + threadIdx.x;
    if (t < T) atomicAdd(&cnt[ac[t]], 1);
}

__global__ __launch_bounds__(256) void k_scanA(const int* __restrict__ cnt,
        int* __restrict__ localExcl, int* __restrict__ blockSums, int E) {
    __shared__ int ls[256];
    const int tid = threadIdx.x;
    int base = blockIdx.x * 1024 + tid * 4;
    int a0 = 0, a1 = 0, a2 = 0, a3 = 0;
    if (base + 3 < E) {
        int4 v = *reinterpret_cast<const int4*>(cnt + base);
        a0 = v.x; a1 = v.y; a2 = v.z; a3 = v.w;
    } else {
        if (base + 0 < E) a0 = cnt[base + 0];
        if (base + 1 < E) a1 = cnt[base + 1];
        if (base + 2 < E) a2 = cnt[base + 2];
        if (base + 3 < E) a3 = cnt[base + 3];
    }
    int tsum = a0 + a1 + a2 + a3;
    ls[tid] = tsum;
    __syncthreads();
    for (int off = 1; off < 256; off <<= 1) {
        int v = (tid >= off) ? ls[tid - off] : 0;
        __syncthreads();
        ls[tid] += v;
        __syncthreads();
    }
    int excl = ls[tid] - tsum;
    if (tid == 255) blockSums[blockIdx.x] = ls[255];
    if (base + 3 < E) {
        int4 o = make_int4(excl, excl + a0, excl + a0 + a1, excl + a0 + a1 + a2);
        *reinterpret_cast<int4*>(localExcl + base) = o;
    } else {
        int run = excl;
        if (base + 0 < E) { localExcl[base + 0] = run; run += a0; }
        if (base + 1 < E) { localExcl[base + 1] = run; run += a1; }
        if (base + 2 < E) { localExcl[base + 2] = run; run += a2; }
        if (base + 3 < E) { localExcl[base + 3] = run; }
    }
}

__global__ __launch_bounds__(256) void k_scanB(int* __restrict__ blockSums, int n) {
    __shared__ int ls[256];
    const int tid = threadIdx.x;
    int v = (tid < n) ? blockSums[tid] : 0;
    ls[tid] = v;
    __syncthreads();
    for (int off = 1; off < 256; off <<= 1) {
        int w = (tid >= off) ? ls[tid - off] : 0;
        __syncthreads();
        ls[tid] += w;
        __syncthreads();
    }
    if (tid < n) blockSums[tid] = ls[tid] - v;   // exclusive
}

// seg[i] = (start, count); cursor[i] = start; chist[min(count,1023)]++
__global__ void k_scanC(const int* __restrict__ localExcl, const int* __restrict__ blockSums,
                        const int* __restrict__ cnt, int2* __restrict__ seg,
                        int* __restrict__ cursor, int* __restrict__ chist, int E) {
    int i = blockIdx.x * blockDim.x + threadIdx.x;
    if (i < E) {
        int s = localExcl[i] + blockSums[i >> 10];
        int c = cnt[i];
        seg[i] = make_int2(s, c);
        cursor[i] = s;
        int b = c < 1023 ? c : 1023;
        atomicAdd(&chist[b], 1);
    }
}

// exclusive scan of chist[1024] -> ccur
__global__ __launch_bounds__(1024) void k_cscan(const int* __restrict__ chist,
                                                int* __restrict__ ccur) {
    __shared__ int ls[1024];
    const int tid = threadIdx.x;
    int v = chist[tid];
    ls[tid] = v;
    __syncthreads();
    for (int off = 1; off < 1024; off <<= 1) {
        int w = (tid >= off) ? ls[tid - off] : 0;
        __syncthreads();
        ls[tid] += w;
        __syncthreads();
    }
    ccur[tid] = ls[tid] - v;
}

// order[]: edges sorted (bucketed) by triangle count
__global__ void k_order(const int2* __restrict__ seg, int* __restrict__ ccur,
                        int* __restrict__ order, int E) {
    int e = blockIdx.x * blockDim.x + threadIdx.x;
    if (e >= E) return;
    int c = seg[e].y;
    int b = c < 1023 ? c : 1023;
    int pos = atomicAdd(&ccur[b], 1);
    order[pos] = e;
}

// tri[pos] = (ab, bc); tte[pos] = et[ab] | et[bc]<<16
__global__ void k_permute(const int* __restrict__ ab, const int* __restrict__ bc,
                          const int* __restrict__ ac, const int* __restrict__ et,
                          int* __restrict__ cursor, int2* __restrict__ tri,
                          int* __restrict__ tte, int T) {
    int t = blockIdx.x * blockDim.x + threadIdx.x;
    if (t >= T) return;
    int a = ab[t], b = bc[t];
    int pos = atomicAdd(&cursor[ac[t]], 1);
    tri[pos] = make_int2(a, b);
    tte[pos] = et[a] | (et[b] << 16);
}

// ---------------- layer-1 message gather: x == fe[et], fe staged in LDS ----------------
// wave = 4 groups of 16 lanes; group owns one (count-sorted) edge; lane sub = 4 dims.
__global__ __launch_bounds__(256) void k_msg1(const int2* __restrict__ seg,
        const int* __restrict__ order, const int* __restrict__ tte,
        const float* __restrict__ fe, float* __restrict__ agg, int E, int nquad) {
    __shared__ float fel[102 * D];      // 25.5 KB
    const int tid = threadIdx.x;
    for (int i = tid; i < 102 * 16; i += 256)
        reinterpret_cast<float4*>(fel)[i] = reinterpret_cast<const float4*>(fe)[i];
    __syncthreads();
    const float4* __restrict__ fel4 = reinterpret_cast<const float4*>(fel);

    const int lane = tid & 63;
    const int sub = lane & 15;
    const int grp = lane >> 4;

    for (int quad = (blockIdx.x * blockDim.x + tid) >> 6; quad * 4 < E; quad += nquad) {
        const int idx = quad * 4 + grp;
        int e = -1;
        int2 sc = make_int2(0, 0);
        if (idx < E) { e = order[idx]; sc = seg[e]; }
        const int s = sc.x, c = sc.y;
        float4 acc = make_float4(0.f, 0.f, 0.f, 0.f);
        for (int i = 0; i < c; ++i) {
            int tt = tte[s + i];
            int ta = tt & 0xffff;
            int tb = ((unsigned)tt) >> 16;
            float4 va = fel4[ta * 16 + sub];
            float4 vb = fel4[tb * 16 + sub];
            acc.x += va.x * vb.x;
            acc.y += va.y * vb.y;
            acc.z += va.z * vb.z;
            acc.w += va.w * vb.w;
        }
        if (e >= 0)
            reinterpret_cast<float4*>(agg + (size_t)e * D)[sub] = acc;
    }
}

// ---------------- layer-2 message gather ----------------
__global__ __launch_bounds__(256) void k_msg4(const int2* __restrict__ seg,
        const int* __restrict__ order, const int2* __restrict__ tri,
        const float* __restrict__ xin, float* __restrict__ agg, int E, int nquad) {
    const int tid = threadIdx.x;
    const int lane = tid & 63;
    const int sub = lane & 15;
    const int grp = lane >> 4;
    const float4* __restrict__ x4 = reinterpret_cast<const float4*>(xin);

    for (int quad = (blockIdx.x * blockDim.x + tid) >> 6; quad * 4 < E; quad += nquad) {
        const int idx = quad * 4 + grp;
        int e = -1;
        int2 sc = make_int2(0, 0);
        if (idx < E) { e = order[idx]; sc = seg[e]; }
        const int s = sc.x, c = sc.y;
        float4 acc = make_float4(0.f, 0.f, 0.f, 0.f);
        for (int i = 0; i < c; ++i) {
            int2 p = tri[s + i];
            float4 va = x4[(size_t)p.x * 16 + sub];
            float4 vb = x4[(size_t)p.y * 16 + sub];
            acc.x += va.x * vb.x;
            acc.y += va.y * vb.y;
            acc.z += va.z * vb.z;
            acc.w += va.w * vb.w;
        }
        if (e >= 0)
            reinterpret_cast<float4*>(agg + (size_t)e * D)[sub] = acc;
    }
}

// ---------------- 64x64 linear + relu (proven round-7 structure) ----------------
#define FPAD 65
__global__ __launch_bounds__(256) void k_linear(const float* __restrict__ in,
        const float* __restrict__ W, const float* __restrict__ b,
        float* __restrict__ outx, int E) {
    __shared__ float Wl[64 * 64];       // 16 KB
    __shared__ float fT[64 * FPAD];     // 16.6 KB, fT[k][r]
    const int tid = threadIdx.x;
    const int row0 = blockIdx.x * 64;

    for (int i = tid; i < 1024; i += 256)
        reinterpret_cast<float4*>(Wl)[i] = reinterpret_cast<const float4*>(W)[i];

    for (int i = tid; i < 1024; i += 256) {
        int r = i >> 4, q = i & 15;
        float4 v = make_float4(0.f, 0.f, 0.f, 0.f);
        if (row0 + r < E)
            v = reinterpret_cast<const float4*>(in + (size_t)(row0 + r) * D)[q];
        fT[(q * 4 + 0) * FPAD + r] = v.x;
        fT[(q * 4 + 1) * FPAD + r] = v.y;
        fT[(q * 4 + 2) * FPAD + r] = v.z;
        fT[(q * 4 + 3) * FPAD + r] = v.w;
    }
    __syncthreads();

    const int j0 = (tid & 15) * 4;
    const int r0 = (tid >> 4) * 4;
    float acc[4][4];
    #pragma unroll
    for (int i = 0; i < 4; ++i)
        #pragma unroll
        for (int j = 0; j < 4; ++j) acc[i][j] = 0.f;

    #pragma unroll 8
    for (int k = 0; k < 64; ++k) {
        float4 f = *reinterpret_cast<const float4*>(&fT[k * FPAD + r0]);
        float4 w = *reinterpret_cast<const float4*>(&Wl[k * 64 + j0]);
        float fa[4] = {f.x, f.y, f.z, f.w};
        float wa[4] = {w.x, w.y, w.z, w.w};
        #pragma unroll
        for (int i = 0; i < 4; ++i)
            #pragma unroll
            for (int j = 0; j < 4; ++j) acc[i][j] += fa[i] * wa[j];
    }

    float4 bv = *reinterpret_cast<const float4*>(&b[j0]);
    float ba[4] = {bv.x, bv.y, bv.z, bv.w};
    #pragma unroll
    for (int i = 0; i < 4; ++i) {
        int row = row0 + r0 + i;
        if (row < E) {
            float4 o;
            o.x = relu_f(acc[i][0] + ba[0]);
            o.y = relu_f(acc[i][1] + ba[1]);
            o.z = relu_f(acc[i][2] + ba[2]);
            o.w = relu_f(acc[i][3] + ba[3]);
            *reinterpret_cast<float4*>(outx + (size_t)row * D + j0) = o;
        }
    }
}

// ---------------- final MLP ----------------
// 256 thr, 128 rows/block, 8 rows x 8 cols per thread (0.375 B/FLOP LDS);
// W1 + fT staged in k-halves. All accesses statically indexed.
#define MPAD 129
__global__ __launch_bounds__(256) void k_mlp(const float* __restrict__ x,
        const int* __restrict__ et, const float* __restrict__ fe,
        const float* __restrict__ W1, const float* __restrict__ b1,
        const float* __restrict__ W2, const float* __restrict__ b2,
        float* __restrict__ out, int E) {
    __shared__ float Wl[64 * 128];      // 32 KB: one k-half of W1
    __shared__ float fT[64 * MPAD];     // 33 KB: fT[k_local][r], 128 rows
    __shared__ float b1l[128];
    __shared__ float W2l[128];
    const int tid = threadIdx.x;
    const int row0 = blockIdx.x * 128;

    if (tid < 128) { b1l[tid] = b1[tid]; W2l[tid] = W2[tid]; }

    const int jt = tid & 15;
    const int j0 = jt * 8;
    const int r0 = (tid >> 4) * 8;
    float acc[8][8];
    #pragma unroll
    for (int i = 0; i < 8; ++i)
        #pragma unroll
        for (int j = 0; j < 8; ++j) acc[i][j] = 0.f;

    for (int h = 0; h < 2; ++h) {
        __syncthreads();   // h=0: order b1l/W2l; h=1: previous half's readers done
        for (int i = tid; i < 2048; i += 256)
            reinterpret_cast<float4*>(Wl)[i] =
                reinterpret_cast<const float4*>(W1 + (size_t)h * 64 * 128)[i];
        for (int i = tid; i < 2048; i += 256) {
            int r = i >> 4, q = i & 15;
            int row = row0 + r;
            float4 v = make_float4(0.f, 0.f, 0.f, 0.f);
            if (row < E) {
                if (h == 0)
                    v = reinterpret_cast<const float4*>(x + (size_t)row * D)[q];
                else
                    v = reinterpret_cast<const float4*>(fe + (size_t)et[row] * D)[q];
            }
            int kb = q * 4;
            fT[(kb + 0) * MPAD + r] = v.x;
            fT[(kb + 1) * MPAD + r] = v.y;
            fT[(kb + 2) * MPAD + r] = v.z;
            fT[(kb + 3) * MPAD + r] = v.w;
        }
        __syncthreads();

        #pragma unroll 2
        for (int k = 0; k < 64; ++k) {
            float4 fA = *reinterpret_cast<const float4*>(&fT[k * MPAD + r0]);
            float4 fB = *reinterpret_cast<const float4*>(&fT[k * MPAD + r0 + 4]);
            float4 wA = *reinterpret_cast<const float4*>(&Wl[k * 128 + j0]);
            float4 wB = *reinterpret_cast<const float4*>(&Wl[k * 128 + j0 + 4]);
            float fa[8] = {fA.x, fA.y, fA.z, fA.w, fB.x, fB.y, fB.z, fB.w};
            float wa[8] = {wA.x, wA.y, wA.z, wA.w, wB.x, wB.y, wB.z, wB.w};
            #pragma unroll
            for (int i = 0; i < 8; ++i)
                #pragma unroll
                for (int j = 0; j < 8; ++j) acc[i][j] += fa[i] * wa[j];
        }
    }

    float4 bA = *reinterpret_cast<const float4*>(&b1l[j0]);
    float4 bB = *reinterpret_cast<const float4*>(&b1l[j0 + 4]);
    float4 wA2 = *reinterpret_cast<const float4*>(&W2l[j0]);
    float4 wB2 = *reinterpret_cast<const float4*>(&W2l[j0 + 4]);
    float ba[8] = {bA.x, bA.y, bA.z, bA.w, bB.x, bB.y, bB.z, bB.w};
    float w2a[8] = {wA2.x, wA2.y, wA2.z, wA2.w, wB2.x, wB2.y, wB2.z, wB2.w};
    float bias2 = b2[0];
    #pragma unroll
    for (int i = 0; i < 8; ++i) {
        float p = 0.f;
        #pragma unroll
        for (int j = 0; j < 8; ++j)
            p += relu_f(acc[i][j] + ba[j]) * w2a[j];
        #pragma unroll
        for (int m = 1; m < 16; m <<= 1) p += __shfl_xor(p, m, 64);
        if (jt == 0) {
            int row = row0 + r0 + i;
            if (row < E) out[row] = p + bias2;
        }
    }
}

extern "C" void kernel_launch(void* const* d_in, const int* in_sizes, int n_in,
                              void* d_out, int out_size, void* d_ws, size_t ws_size,
                              hipStream_t stream) {
    const int*   edge_type = (const int*)d_in[0];
    const int*   ab        = (const int*)d_in[1];
    const int*   bc        = (const int*)d_in[2];
    const int*   ac        = (const int*)d_in[3];
    const float* fe        = (const float*)d_in[4];
    const float* W1        = (const float*)d_in[5];
    const float* b1        = (const float*)d_in[6];
    const float* W2        = (const float*)d_in[7];
    const float* b2        = (const float*)d_in[8];
    const float* mW1       = (const float*)d_in[9];
    const float* mb1       = (const float*)d_in[10];
    const float* mW2       = (const float*)d_in[11];
    const float* mb2       = (const float*)d_in[12];

    const int E = in_sizes[0];
    const int T = in_sizes[1];
    float* out = (float*)d_out;

    // workspace layout
    char* p = (char*)d_ws;
    float* xa   = (float*)p;   p += (size_t)E * D * sizeof(float);
    float* xb   = (float*)p;   p += (size_t)E * D * sizeof(float);
    float* agg  = (float*)p;   p += (size_t)E * D * sizeof(float);
    int* cnt    = (int*)p;     p += (size_t)E * sizeof(int);
    int* lexcl  = (int*)p;     p += (size_t)E * sizeof(int);
    int* cursor = (int*)p;     p += (size_t)E * sizeof(int);
    int* order  = (int*)p;     p += (size_t)E * sizeof(int);
    int* bsums  = (int*)p;     p += 256 * sizeof(int);
    int* chist  = (int*)p;     p += 1024 * sizeof(int);
    int* ccur   = (int*)p;     p += 1024 * sizeof(int);
    int2* seg   = (int2*)p;    p += (size_t)E * sizeof(int2);
    int2* tri   = (int2*)p;    p += (size_t)T * sizeof(int2);
    int* tte    = (int*)p;     p += (size_t)T * sizeof(int);

    const int nblkA = (E + 1023) / 1024;

    // CSR of triangles keyed by ac + count-sorted edge order
    hipMemsetAsync(cnt, 0, (size_t)E * sizeof(int), stream);
    hipMemsetAsync(chist, 0, 1024 * sizeof(int), stream);
    k_hist<<<(T + 255) / 256, 256, 0, stream>>>(ac, cnt, T);
    k_scanA<<<nblkA, 256, 0, stream>>>(cnt, lexcl, bsums, E);
    k_scanB<<<1, 256, 0, stream>>>(bsums, nblkA);
    k_scanC<<<(E + 255) / 256, 256, 0, stream>>>(lexcl, bsums, cnt, seg, cursor, chist, E);
    k_cscan<<<1, 1024, 0, stream>>>(chist, ccur);
    k_order<<<(E + 255) / 256, 256, 0, stream>>>(seg, ccur, order, E);
    k_permute<<<(T + 255) / 256, 256, 0, stream>>>(ab, bc, ac, edge_type, cursor, tri, tte, T);

    const int MSG_BLOCKS = 2048;
    const int nquad = MSG_BLOCKS * 256 / 64;   // one wave per 4 edges
    // layer 1 (x == fe[et], read straight from LDS-staged fact_emb)
    k_msg1<<<MSG_BLOCKS, 256, 0, stream>>>(seg, order, tte, fe, agg, E, nquad);
    k_linear<<<(E + 63) / 64, 256, 0, stream>>>(agg, W1, b1, xb, E);
    // layer 2
    k_msg4<<<MSG_BLOCKS, 256, 0, stream>>>(seg, order, tri, xb, agg, E, nquad);
    k_linear<<<(E + 63) / 64, 256, 0, stream>>>(agg, W2, b2, xa, E);

    k_mlp<<<(E + 127) / 128, 256, 0, stream>>>(xa, edge_type, fe, mW1, mb1, mW2, mb2, out, E);
}

// Round 9
// 231.610 us; speedup vs baseline: 4.3164x; 4.3164x over previous
//
#include <hip/hip_runtime.h>

#define D 64

__device__ __forceinline__ float relu_f(float v) { return v > 0.f ? v : 0.f; }

// ---------------- CSR build: histogram + 3-pass scan + permute ----------------

__global__ void k_hist(const int* __restrict__ ac, int* __restrict__ cnt, int T) {
    int t = blockIdx.x * blockDim.x + threadIdx.x;
    if (t < T) atomicAdd(&cnt[ac[t]], 1);
}

__global__ __launch_bounds__(256) void k_scanA(const int* __restrict__ cnt,
        int* __restrict__ localExcl, int* __restrict__ blockSums, int E) {
    __shared__ int ls[256];
    const int tid = threadIdx.x;
    int base = blockIdx.x * 1024 + tid * 4;
    int a0 = 0, a1 = 0, a2 = 0, a3 = 0;
    if (base + 3 < E) {
        int4 v = *reinterpret_cast<const int4*>(cnt + base);
        a0 = v.x; a1 = v.y; a2 = v.z; a3 = v.w;
    } else {
        if (base + 0 < E) a0 = cnt[base + 0];
        if (base + 1 < E) a1 = cnt[base + 1];
        if (base + 2 < E) a2 = cnt[base + 2];
        if (base + 3 < E) a3 = cnt[base + 3];
    }
    int tsum = a0 + a1 + a2 + a3;
    ls[tid] = tsum;
    __syncthreads();
    for (int off = 1; off < 256; off <<= 1) {
        int v = (tid >= off) ? ls[tid - off] : 0;
        __syncthreads();
        ls[tid] += v;
        __syncthreads();
    }
    int excl = ls[tid] - tsum;
    if (tid == 255) blockSums[blockIdx.x] = ls[255];
    if (base + 3 < E) {
        int4 o = make_int4(excl, excl + a0, excl + a0 + a1, excl + a0 + a1 + a2);
        *reinterpret_cast<int4*>(localExcl + base) = o;
    } else {
        int run = excl;
        if (base + 0 < E) { localExcl[base + 0] = run; run += a0; }
        if (base + 1 < E) { localExcl[base + 1] = run; run += a1; }
        if (base + 2 < E) { localExcl[base + 2] = run; run += a2; }
        if (base + 3 < E) { localExcl[base + 3] = run; }
    }
}

__global__ __launch_bounds__(256) void k_scanB(int* __restrict__ blockSums, int n) {
    __shared__ int ls[256];
    const int tid = threadIdx.x;
    int v = (tid < n) ? blockSums[tid] : 0;
    ls[tid] = v;
    __syncthreads();
    for (int off = 1; off < 256; off <<= 1) {
        int w = (tid >= off) ? ls[tid - off] : 0;
        __syncthreads();
        ls[tid] += w;
        __syncthreads();
    }
    if (tid < n) blockSums[tid] = ls[tid] - v;   // exclusive
}

// seg[i] = (start, count); cursor[i] = start
__global__ void k_scanC(const int* __restrict__ localExcl, const int* __restrict__ blockSums,
                        const int* __restrict__ cnt, int2* __restrict__ seg,
                        int* __restrict__ cursor, int E) {
    int i = blockIdx.x * blockDim.x + threadIdx.x;
    if (i < E) {
        int s = localExcl[i] + blockSums[i >> 10];
        seg[i] = make_int2(s, cnt[i]);
        cursor[i] = s;
    }
}

// tri[pos] = (ab, bc); tte[pos] = et[ab] | et[bc]<<16
__global__ void k_permute(const int* __restrict__ ab, const int* __restrict__ bc,
                          const int* __restrict__ ac, const int* __restrict__ et,
                          int* __restrict__ cursor, int2* __restrict__ tri,
                          int* __restrict__ tte, int T) {
    int t = blockIdx.x * blockDim.x + threadIdx.x;
    if (t >= T) return;
    int a = ab[t], b = bc[t];
    int pos = atomicAdd(&cursor[ac[t]], 1);
    tri[pos] = make_int2(a, b);
    tte[pos] = et[a] | (et[b] << 16);
}

// ---------------- layer-1 message gather: x == fe[et], fe staged in LDS ----------------
// wave = 4 groups of 16 lanes; group g owns edge quad*4+g; lane sub = 4 dims.
__global__ __launch_bounds__(256) void k_msg1(const int2* __restrict__ seg,
        const int* __restrict__ tte, const float* __restrict__ fe,
        float* __restrict__ agg, int E, int nquad) {
    __shared__ float fel[102 * D];      // 25.5 KB
    const int tid = threadIdx.x;
    for (int i = tid; i < 102 * 16; i += 256)
        reinterpret_cast<float4*>(fel)[i] = reinterpret_cast<const float4*>(fe)[i];
    __syncthreads();
    const float4* __restrict__ fel4 = reinterpret_cast<const float4*>(fel);

    const int lane = tid & 63;
    const int sub = lane & 15;
    const int grp = lane >> 4;

    for (int quad = (blockIdx.x * blockDim.x + tid) >> 6; quad * 4 < E; quad += nquad) {
        const int e = quad * 4 + grp;
        int2 sc = make_int2(0, 0);
        if (e < E) sc = seg[e];
        const int s = sc.x, c = sc.y;
        float4 acc = make_float4(0.f, 0.f, 0.f, 0.f);
        for (int i = 0; i < c; ++i) {
            int tt = tte[s + i];
            int ta = tt & 0xffff;
            int tb = ((unsigned)tt) >> 16;
            float4 va = fel4[ta * 16 + sub];
            float4 vb = fel4[tb * 16 + sub];
            acc.x += va.x * vb.x;
            acc.y += va.y * vb.y;
            acc.z += va.z * vb.z;
            acc.w += va.w * vb.w;
        }
        if (e < E)
            reinterpret_cast<float4*>(agg + (size_t)e * D)[sub] = acc;
    }
}

// ---------------- layer-2 message gather ----------------
__global__ __launch_bounds__(256) void k_msg4(const int2* __restrict__ seg,
        const int2* __restrict__ tri, const float* __restrict__ xin,
        float* __restrict__ agg, int E, int nquad) {
    const int tid = threadIdx.x;
    const int lane = tid & 63;
    const int sub = lane & 15;
    const int grp = lane >> 4;
    const float4* __restrict__ x4 = reinterpret_cast<const float4*>(xin);

    for (int quad = (blockIdx.x * blockDim.x + tid) >> 6; quad * 4 < E; quad += nquad) {
        const int e = quad * 4 + grp;
        int2 sc = make_int2(0, 0);
        if (e < E) sc = seg[e];
        const int s = sc.x, c = sc.y;
        float4 acc = make_float4(0.f, 0.f, 0.f, 0.f);
        for (int i = 0; i < c; ++i) {       // divergent across groups: exec-masked
            int2 p = tri[s + i];
            float4 va = x4[(size_t)p.x * 16 + sub];
            float4 vb = x4[(size_t)p.y * 16 + sub];
            acc.x += va.x * vb.x;
            acc.y += va.y * vb.y;
            acc.z += va.z * vb.z;
            acc.w += va.w * vb.w;
        }
        if (e < E)
            reinterpret_cast<float4*>(agg + (size_t)e * D)[sub] = acc;
    }
}

// ---------------- 64x64 linear + relu (proven round-7 structure) ----------------
#define FPAD 65
__global__ __launch_bounds__(256) void k_linear(const float* __restrict__ in,
        const float* __restrict__ W, const float* __restrict__ b,
        float* __restrict__ outx, int E) {
    __shared__ float Wl[64 * 64];       // 16 KB
    __shared__ float fT[64 * FPAD];     // 16.6 KB, fT[k][r]
    const int tid = threadIdx.x;
    const int row0 = blockIdx.x * 64;

    for (int i = tid; i < 1024; i += 256)
        reinterpret_cast<float4*>(Wl)[i] = reinterpret_cast<const float4*>(W)[i];

    for (int i = tid; i < 1024; i += 256) {
        int r = i >> 4, q = i & 15;
        float4 v = make_float4(0.f, 0.f, 0.f, 0.f);
        if (row0 + r < E)
            v = reinterpret_cast<const float4*>(in + (size_t)(row0 + r) * D)[q];
        fT[(q * 4 + 0) * FPAD + r] = v.x;
        fT[(q * 4 + 1) * FPAD + r] = v.y;
        fT[(q * 4 + 2) * FPAD + r] = v.z;
        fT[(q * 4 + 3) * FPAD + r] = v.w;
    }
    __syncthreads();

    const int j0 = (tid & 15) * 4;
    const int r0 = (tid >> 4) * 4;
    float acc[4][4];
    #pragma unroll
    for (int i = 0; i < 4; ++i)
        #pragma unroll
        for (int j = 0; j < 4; ++j) acc[i][j] = 0.f;

    #pragma unroll 8
    for (int k = 0; k < 64; ++k) {
        float4 f = *reinterpret_cast<const float4*>(&fT[k * FPAD + r0]);
        float4 w = *reinterpret_cast<const float4*>(&Wl[k * 64 + j0]);
        float fa[4] = {f.x, f.y, f.z, f.w};
        float wa[4] = {w.x, w.y, w.z, w.w};
        #pragma unroll
        for (int i = 0; i < 4; ++i)
            #pragma unroll
            for (int j = 0; j < 4; ++j) acc[i][j] += fa[i] * wa[j];
    }

    float4 bv = *reinterpret_cast<const float4*>(&b[j0]);
    float ba[4] = {bv.x, bv.y, bv.z, bv.w};
    #pragma unroll
    for (int i = 0; i < 4; ++i) {
        int row = row0 + r0 + i;
        if (row < E) {
            float4 o;
            o.x = relu_f(acc[i][0] + ba[0]);
            o.y = relu_f(acc[i][1] + ba[1]);
            o.z = relu_f(acc[i][2] + ba[2]);
            o.w = relu_f(acc[i][3] + ba[3]);
            *reinterpret_cast<float4*>(outx + (size_t)row * D + j0) = o;
        }
    }
}

// ---------------- final MLP ----------------
// 256 thr, 128 rows/block, 8 rows x 8 cols per thread (0.375 B/FLOP LDS);
// W1 + fT staged in k-halves. All accesses statically indexed.
#define MPAD 129
__global__ __launch_bounds__(256) void k_mlp(const float* __restrict__ x,
        const int* __restrict__ et, const float* __restrict__ fe,
        const float* __restrict__ W1, const float* __restrict__ b1,
        const float* __restrict__ W2, const float* __restrict__ b2,
        float* __restrict__ out, int E) {
    __shared__ float Wl[64 * 128];      // 32 KB: one k-half of W1
    __shared__ float fT[64 * MPAD];     // 33 KB: fT[k_local][r], 128 rows
    __shared__ float b1l[128];
    __shared__ float W2l[128];
    const int tid = threadIdx.x;
    const int row0 = blockIdx.x * 128;

    if (tid < 128) { b1l[tid] = b1[tid]; W2l[tid] = W2[tid]; }

    const int jt = tid & 15;
    const int j0 = jt * 8;
    const int r0 = (tid >> 4) * 8;
    float acc[8][8];
    #pragma unroll
    for (int i = 0; i < 8; ++i)
        #pragma unroll
        for (int j = 0; j < 8; ++j) acc[i][j] = 0.f;

    for (int h = 0; h < 2; ++h) {
        __syncthreads();   // h=0: order b1l/W2l; h=1: previous half's readers done
        for (int i = tid; i < 2048; i += 256)
            reinterpret_cast<float4*>(Wl)[i] =
                reinterpret_cast<const float4*>(W1 + (size_t)h * 64 * 128)[i];
        for (int i = tid; i < 2048; i += 256) {
            int r = i >> 4, q = i & 15;
            int row = row0 + r;
            float4 v = make_float4(0.f, 0.f, 0.f, 0.f);
            if (row < E) {
                if (h == 0)
                    v = reinterpret_cast<const float4*>(x + (size_t)row * D)[q];
                else
                    v = reinterpret_cast<const float4*>(fe + (size_t)et[row] * D)[q];
            }
            int kb = q * 4;
            fT[(kb + 0) * MPAD + r] = v.x;
            fT[(kb + 1) * MPAD + r] = v.y;
            fT[(kb + 2) * MPAD + r] = v.z;
            fT[(kb + 3) * MPAD + r] = v.w;
        }
        __syncthreads();

        #pragma unroll 2
        for (int k = 0; k < 64; ++k) {
            float4 fA = *reinterpret_cast<const float4*>(&fT[k * MPAD + r0]);
            float4 fB = *reinterpret_cast<const float4*>(&fT[k * MPAD + r0 + 4]);
            float4 wA = *reinterpret_cast<const float4*>(&Wl[k * 128 + j0]);
            float4 wB = *reinterpret_cast<const float4*>(&Wl[k * 128 + j0 + 4]);
            float fa[8] = {fA.x, fA.y, fA.z, fA.w, fB.x, fB.y, fB.z, fB.w};
            float wa[8] = {wA.x, wA.y, wA.z, wA.w, wB.x, wB.y, wB.z, wB.w};
            #pragma unroll
            for (int i = 0; i < 8; ++i)
                #pragma unroll
                for (int j = 0; j < 8; ++j) acc[i][j] += fa[i] * wa[j];
        }
    }

    float4 bA = *reinterpret_cast<const float4*>(&b1l[j0]);
    float4 bB = *reinterpret_cast<const float4*>(&b1l[j0 + 4]);
    float4 wA2 = *reinterpret_cast<const float4*>(&W2l[j0]);
    float4 wB2 = *reinterpret_cast<const float4*>(&W2l[j0 + 4]);
    float ba[8] = {bA.x, bA.y, bA.z, bA.w, bB.x, bB.y, bB.z, bB.w};
    float w2a[8] = {wA2.x, wA2.y, wA2.z, wA2.w, wB2.x, wB2.y, wB2.z, wB2.w};
    float bias2 = b2[0];
    #pragma unroll
    for (int i = 0; i < 8; ++i) {
        float p = 0.f;
        #pragma unroll
        for (int j = 0; j < 8; ++j)
            p += relu_f(acc[i][j] + ba[j]) * w2a[j];
        #pragma unroll
        for (int m = 1; m < 16; m <<= 1) p += __shfl_xor(p, m, 64);
        if (jt == 0) {
            int row = row0 + r0 + i;
            if (row < E) out[row] = p + bias2;
        }
    }
}

extern "C" void kernel_launch(void* const* d_in, const int* in_sizes, int n_in,
                              void* d_out, int out_size, void* d_ws, size_t ws_size,
                              hipStream_t stream) {
    const int*   edge_type = (const int*)d_in[0];
    const int*   ab        = (const int*)d_in[1];
    const int*   bc        = (const int*)d_in[2];
    const int*   ac        = (const int*)d_in[3];
    const float* fe        = (const float*)d_in[4];
    const float* W1        = (const float*)d_in[5];
    const float* b1        = (const float*)d_in[6];
    const float* W2        = (const float*)d_in[7];
    const float* b2        = (const float*)d_in[8];
    const float* mW1       = (const float*)d_in[9];
    const float* mb1       = (const float*)d_in[10];
    const float* mW2       = (const float*)d_in[11];
    const float* mb2       = (const float*)d_in[12];

    const int E = in_sizes[0];
    const int T = in_sizes[1];
    float* out = (float*)d_out;

    // workspace layout
    char* p = (char*)d_ws;
    float* xa   = (float*)p;   p += (size_t)E * D * sizeof(float);
    float* xb   = (float*)p;   p += (size_t)E * D * sizeof(float);
    float* agg  = (float*)p;   p += (size_t)E * D * sizeof(float);
    int* cnt    = (int*)p;     p += (size_t)E * sizeof(int);
    int* lexcl  = (int*)p;     p += (size_t)E * sizeof(int);
    int* cursor = (int*)p;     p += (size_t)E * sizeof(int);
    int* bsums  = (int*)p;     p += 256 * sizeof(int);
    int2* seg   = (int2*)p;    p += (size_t)E * sizeof(int2);
    int2* tri   = (int2*)p;    p += (size_t)T * sizeof(int2);
    int* tte    = (int*)p;     p += (size_t)T * sizeof(int);

    const int nblkA = (E + 1023) / 1024;

    // CSR of triangles keyed by ac (reused by both layers)
    hipMemsetAsync(cnt, 0, (size_t)E * sizeof(int), stream);
    k_hist<<<(T + 255) / 256, 256, 0, stream>>>(ac, cnt, T);
    k_scanA<<<nblkA, 256, 0, stream>>>(cnt, lexcl, bsums, E);
    k_scanB<<<1, 256, 0, stream>>>(bsums, nblkA);
    k_scanC<<<(E + 255) / 256, 256, 0, stream>>>(lexcl, bsums, cnt, seg, cursor, E);
    k_permute<<<(T + 255) / 256, 256, 0, stream>>>(ab, bc, ac, edge_type, cursor, tri, tte, T);

    const int MSG_BLOCKS = 2048;
    const int nquad = MSG_BLOCKS * 256 / 64;   // one wave per 4 edges
    // layer 1 (x == fe[et], read straight from LDS-staged fact_emb)
    k_msg1<<<MSG_BLOCKS, 256, 0, stream>>>(seg, tte, fe, agg, E, nquad);
    k_linear<<<(E + 63) / 64, 256, 0, stream>>>(agg, W1, b1, xb, E);
    // layer 2
    k_msg4<<<MSG_BLOCKS, 256, 0, stream>>>(seg, tri, xb, agg, E, nquad);
    k_linear<<<(E + 63) / 64, 256, 0, stream>>>(agg, W2, b2, xa, E);

    k_mlp<<<(E + 127) / 128, 256, 0, stream>>>(xa, edge_type, fe, mW1, mb1, mW2, mb2, out, E);
}

// Round 10
// 214.383 us; speedup vs baseline: 4.6632x; 1.0804x over previous
//
#include <hip/hip_runtime.h>

#define D 64

__device__ __forceinline__ float relu_f(float v) { return v > 0.f ? v : 0.f; }

// ---------------- CSR build: histogram + 3-pass scan + permute ----------------

__global__ void k_hist(const int* __restrict__ ac, int* __restrict__ cnt, int T) {
    int t = blockIdx.x * blockDim.x + threadIdx.x;
    if (t < T) atomicAdd(&cnt[ac[t]], 1);
}

__global__ __launch_bounds__(256) void k_scanA(const int* __restrict__ cnt,
        int* __restrict__ localExcl, int* __restrict__ blockSums, int E) {
    __shared__ int ls[256];
    const int tid = threadIdx.x;
    int base = blockIdx.x * 1024 + tid * 4;
    int a0 = 0, a1 = 0, a2 = 0, a3 = 0;
    if (base + 3 < E) {
        int4 v = *reinterpret_cast<const int4*>(cnt + base);
        a0 = v.x; a1 = v.y; a2 = v.z; a3 = v.w;
    } else {
        if (base + 0 < E) a0 = cnt[base + 0];
        if (base + 1 < E) a1 = cnt[base + 1];
        if (base + 2 < E) a2 = cnt[base + 2];
        if (base + 3 < E) a3 = cnt[base + 3];
    }
    int tsum = a0 + a1 + a2 + a3;
    ls[tid] = tsum;
    __syncthreads();
    for (int off = 1; off < 256; off <<= 1) {
        int v = (tid >= off) ? ls[tid - off] : 0;
        __syncthreads();
        ls[tid] += v;
        __syncthreads();
    }
    int excl = ls[tid] - tsum;
    if (tid == 255) blockSums[blockIdx.x] = ls[255];
    if (base + 3 < E) {
        int4 o = make_int4(excl, excl + a0, excl + a0 + a1, excl + a0 + a1 + a2);
        *reinterpret_cast<int4*>(localExcl + base) = o;
    } else {
        int run = excl;
        if (base + 0 < E) { localExcl[base + 0] = run; run += a0; }
        if (base + 1 < E) { localExcl[base + 1] = run; run += a1; }
        if (base + 2 < E) { localExcl[base + 2] = run; run += a2; }
        if (base + 3 < E) { localExcl[base + 3] = run; }
    }
}

__global__ __launch_bounds__(256) void k_scanB(int* __restrict__ blockSums, int n) {
    __shared__ int ls[256];
    const int tid = threadIdx.x;
    int v = (tid < n) ? blockSums[tid] : 0;
    ls[tid] = v;
    __syncthreads();
    for (int off = 1; off < 256; off <<= 1) {
        int w = (tid >= off) ? ls[tid - off] : 0;
        __syncthreads();
        ls[tid] += w;
        __syncthreads();
    }
    if (tid < n) blockSums[tid] = ls[tid] - v;   // exclusive
}

// seg[i] = (start, count); cursor[i] = start
__global__ void k_scanC(const int* __restrict__ localExcl, const int* __restrict__ blockSums,
                        const int* __restrict__ cnt, int2* __restrict__ seg,
                        int* __restrict__ cursor, int E) {
    int i = blockIdx.x * blockDim.x + threadIdx.x;
    if (i < E) {
        int s = localExcl[i] + blockSums[i >> 10];
        seg[i] = make_int2(s, cnt[i]);
        cursor[i] = s;
    }
}

// tri[pos] = (ab, bc); tte[pos] = et[ab] | et[bc]<<16
__global__ void k_permute(const int* __restrict__ ab, const int* __restrict__ bc,
                          const int* __restrict__ ac, const int* __restrict__ et,
                          int* __restrict__ cursor, int2* __restrict__ tri,
                          int* __restrict__ tte, int T) {
    int t = blockIdx.x * blockDim.x + threadIdx.x;
    if (t >= T) return;
    int a = ab[t], b = bc[t];
    int pos = atomicAdd(&cursor[ac[t]], 1);
    tri[pos] = make_int2(a, b);
    tte[pos] = et[a] | (et[b] << 16);
}

// ---------------- layer-1 message gather: x == fe[et], fe staged in LDS ----------------
// wave = 4 groups of 16 lanes; group g owns edge quad*4+g; lane sub = 4 dims.
__global__ __launch_bounds__(256) void k_msg1(const int2* __restrict__ seg,
        const int* __restrict__ tte, const float* __restrict__ fe,
        float* __restrict__ agg, int E, int nquad) {
    __shared__ float fel[102 * D];      // 25.5 KB
    const int tid = threadIdx.x;
    for (int i = tid; i < 102 * 16; i += 256)
        reinterpret_cast<float4*>(fel)[i] = reinterpret_cast<const float4*>(fe)[i];
    __syncthreads();
    const float4* __restrict__ fel4 = reinterpret_cast<const float4*>(fel);

    const int lane = tid & 63;
    const int sub = lane & 15;
    const int grp = lane >> 4;

    for (int quad = (blockIdx.x * blockDim.x + tid) >> 6; quad * 4 < E; quad += nquad) {
        const int e = quad * 4 + grp;
        int2 sc = make_int2(0, 0);
        if (e < E) sc = seg[e];
        const int s = sc.x, c = sc.y;
        float4 acc = make_float4(0.f, 0.f, 0.f, 0.f);
        int i = 0;
        for (; i + 1 < c; i += 2) {
            int tt0 = tte[s + i], tt1 = tte[s + i + 1];
            float4 va0 = fel4[(tt0 & 0xffff) * 16 + sub];
            float4 vb0 = fel4[(((unsigned)tt0) >> 16) * 16 + sub];
            float4 va1 = fel4[(tt1 & 0xffff) * 16 + sub];
            float4 vb1 = fel4[(((unsigned)tt1) >> 16) * 16 + sub];
            acc.x += va0.x * vb0.x;
            acc.y += va0.y * vb0.y;
            acc.z += va0.z * vb0.z;
            acc.w += va0.w * vb0.w;
            acc.x += va1.x * vb1.x;
            acc.y += va1.y * vb1.y;
            acc.z += va1.z * vb1.z;
            acc.w += va1.w * vb1.w;
        }
        if (i < c) {
            int tt = tte[s + i];
            float4 va = fel4[(tt & 0xffff) * 16 + sub];
            float4 vb = fel4[(((unsigned)tt) >> 16) * 16 + sub];
            acc.x += va.x * vb.x;
            acc.y += va.y * vb.y;
            acc.z += va.z * vb.z;
            acc.w += va.w * vb.w;
        }
        if (e < E)
            reinterpret_cast<float4*>(agg + (size_t)e * D)[sub] = acc;
    }
}

// ---------------- layer-2 message gather (unroll-4, batched loads) ----------------
__global__ __launch_bounds__(256) void k_msg4(const int2* __restrict__ seg,
        const int2* __restrict__ tri, const float* __restrict__ xin,
        float* __restrict__ agg, int E, int nquad) {
    const int tid = threadIdx.x;
    const int lane = tid & 63;
    const int sub = lane & 15;
    const int grp = lane >> 4;
    const float4* __restrict__ x4 = reinterpret_cast<const float4*>(xin);

    for (int quad = (blockIdx.x * blockDim.x + tid) >> 6; quad * 4 < E; quad += nquad) {
        const int e = quad * 4 + grp;
        int2 sc = make_int2(0, 0);
        if (e < E) sc = seg[e];
        const int s = sc.x, c = sc.y;
        float4 acc = make_float4(0.f, 0.f, 0.f, 0.f);
        int i = 0;
        for (; i + 3 < c; i += 4) {     // 4 tri loads, then 8 independent gathers
            int2 p0 = tri[s + i + 0];
            int2 p1 = tri[s + i + 1];
            int2 p2 = tri[s + i + 2];
            int2 p3 = tri[s + i + 3];
            float4 va0 = x4[(size_t)p0.x * 16 + sub];
            float4 vb0 = x4[(size_t)p0.y * 16 + sub];
            float4 va1 = x4[(size_t)p1.x * 16 + sub];
            float4 vb1 = x4[(size_t)p1.y * 16 + sub];
            float4 va2 = x4[(size_t)p2.x * 16 + sub];
            float4 vb2 = x4[(size_t)p2.y * 16 + sub];
            float4 va3 = x4[(size_t)p3.x * 16 + sub];
            float4 vb3 = x4[(size_t)p3.y * 16 + sub];
            acc.x += va0.x * vb0.x; acc.y += va0.y * vb0.y;
            acc.z += va0.z * vb0.z; acc.w += va0.w * vb0.w;
            acc.x += va1.x * vb1.x; acc.y += va1.y * vb1.y;
            acc.z += va1.z * vb1.z; acc.w += va1.w * vb1.w;
            acc.x += va2.x * vb2.x; acc.y += va2.y * vb2.y;
            acc.z += va2.z * vb2.z; acc.w += va2.w * vb2.w;
            acc.x += va3.x * vb3.x; acc.y += va3.y * vb3.y;
            acc.z += va3.z * vb3.z; acc.w += va3.w * vb3.w;
        }
        for (; i < c; ++i) {
            int2 p = tri[s + i];
            float4 va = x4[(size_t)p.x * 16 + sub];
            float4 vb = x4[(size_t)p.y * 16 + sub];
            acc.x += va.x * vb.x;
            acc.y += va.y * vb.y;
            acc.z += va.z * vb.z;
            acc.w += va.w * vb.w;
        }
        if (e < E)
            reinterpret_cast<float4*>(agg + (size_t)e * D)[sub] = acc;
    }
}

// ---------------- 64x64 linear + relu (proven round-7 structure) ----------------
#define FPAD 65
__global__ __launch_bounds__(256) void k_linear(const float* __restrict__ in,
        const float* __restrict__ W, const float* __restrict__ b,
        float* __restrict__ outx, int E) {
    __shared__ float Wl[64 * 64];       // 16 KB
    __shared__ float fT[64 * FPAD];     // 16.6 KB, fT[k][r]
    const int tid = threadIdx.x;
    const int row0 = blockIdx.x * 64;

    for (int i = tid; i < 1024; i += 256)
        reinterpret_cast<float4*>(Wl)[i] = reinterpret_cast<const float4*>(W)[i];

    for (int i = tid; i < 1024; i += 256) {
        int r = i >> 4, q = i & 15;
        float4 v = make_float4(0.f, 0.f, 0.f, 0.f);
        if (row0 + r < E)
            v = reinterpret_cast<const float4*>(in + (size_t)(row0 + r) * D)[q];
        fT[(q * 4 + 0) * FPAD + r] = v.x;
        fT[(q * 4 + 1) * FPAD + r] = v.y;
        fT[(q * 4 + 2) * FPAD + r] = v.z;
        fT[(q * 4 + 3) * FPAD + r] = v.w;
    }
    __syncthreads();

    const int j0 = (tid & 15) * 4;
    const int r0 = (tid >> 4) * 4;
    float acc[4][4];
    #pragma unroll
    for (int i = 0; i < 4; ++i)
        #pragma unroll
        for (int j = 0; j < 4; ++j) acc[i][j] = 0.f;

    #pragma unroll 8
    for (int k = 0; k < 64; ++k) {
        float4 f = *reinterpret_cast<const float4*>(&fT[k * FPAD + r0]);
        float4 w = *reinterpret_cast<const float4*>(&Wl[k * 64 + j0]);
        float fa[4] = {f.x, f.y, f.z, f.w};
        float wa[4] = {w.x, w.y, w.z, w.w};
        #pragma unroll
        for (int i = 0; i < 4; ++i)
            #pragma unroll
            for (int j = 0; j < 4; ++j) acc[i][j] += fa[i] * wa[j];
    }

    float4 bv = *reinterpret_cast<const float4*>(&b[j0]);
    float ba[4] = {bv.x, bv.y, bv.z, bv.w};
    #pragma unroll
    for (int i = 0; i < 4; ++i) {
        int row = row0 + r0 + i;
        if (row < E) {
            float4 o;
            o.x = relu_f(acc[i][0] + ba[0]);
            o.y = relu_f(acc[i][1] + ba[1]);
            o.z = relu_f(acc[i][2] + ba[2]);
            o.w = relu_f(acc[i][3] + ba[3]);
            *reinterpret_cast<float4*>(outx + (size_t)row * D + j0) = o;
        }
    }
}

// ---------------- final MLP (K-quartered: ~34KB LDS -> 4 blocks/CU) ----------------
// 512 thr, 128 rows/block, 8 rows x 4 cols per thread; per K-quarter stage
// Wl[32][128] + fT[32][129], then 32-k compute. h: 0,1 = x halves; 2,3 = fe halves.
#define MPAD 129
__global__ __launch_bounds__(512) void k_mlp(const float* __restrict__ x,
        const int* __restrict__ et, const float* __restrict__ fe,
        const float* __restrict__ W1, const float* __restrict__ b1,
        const float* __restrict__ W2, const float* __restrict__ b2,
        float* __restrict__ out, int E) {
    __shared__ float Wl[32 * 128];      // 16 KB: one k-quarter of W1
    __shared__ float fT[32 * MPAD];     // 16.5 KB: fT[k_local][r], 128 rows
    __shared__ float b1l[128];
    __shared__ float W2l[128];
    const int tid = threadIdx.x;
    const int row0 = blockIdx.x * 128;

    if (tid < 128) { b1l[tid] = b1[tid]; W2l[tid] = W2[tid]; }

    const int jt = tid & 31;
    const int j0 = jt * 4;
    const int r0 = (tid >> 5) * 8;
    float acc[8][4];
    #pragma unroll
    for (int i = 0; i < 8; ++i)
        #pragma unroll
        for (int j = 0; j < 4; ++j) acc[i][j] = 0.f;

    for (int h = 0; h < 4; ++h) {
        __syncthreads();   // prev quarter's readers done (h=0: orders b1l/W2l too)
        // stage W1 k-quarter: rows h*32..h*32+31 (row-major, contiguous)
        for (int i = tid; i < 1024; i += 512)
            reinterpret_cast<float4*>(Wl)[i] =
                reinterpret_cast<const float4*>(W1 + (size_t)h * 32 * 128)[i];
        // stage features transposed: 128 rows x 8 float4 (32 cols)
        for (int i = tid; i < 1024; i += 512) {
            int r = i >> 3, q = i & 7;
            int row = row0 + r;
            float4 v = make_float4(0.f, 0.f, 0.f, 0.f);
            if (row < E) {
                int fq = (h & 1) * 8 + q;        // float4 index within 64-col source
                if (h < 2)
                    v = reinterpret_cast<const float4*>(x + (size_t)row * D)[fq];
                else
                    v = reinterpret_cast<const float4*>(fe + (size_t)et[row] * D)[fq];
            }
            int kb = q * 4;
            fT[(kb + 0) * MPAD + r] = v.x;
            fT[(kb + 1) * MPAD + r] = v.y;
            fT[(kb + 2) * MPAD + r] = v.z;
            fT[(kb + 3) * MPAD + r] = v.w;
        }
        __syncthreads();

        #pragma unroll 4
        for (int k = 0; k < 32; ++k) {
            float4 fA = *reinterpret_cast<const float4*>(&fT[k * MPAD + r0]);
            float4 fB = *reinterpret_cast<const float4*>(&fT[k * MPAD + r0 + 4]);
            float4 w = *reinterpret_cast<const float4*>(&Wl[k * 128 + j0]);
            float fa[8] = {fA.x, fA.y, fA.z, fA.w, fB.x, fB.y, fB.z, fB.w};
            float wa[4] = {w.x, w.y, w.z, w.w};
            #pragma unroll
            for (int i = 0; i < 8; ++i)
                #pragma unroll
                for (int j = 0; j < 4; ++j) acc[i][j] += fa[i] * wa[j];
        }
    }

    float4 bv = *reinterpret_cast<const float4*>(&b1l[j0]);
    float4 w2 = *reinterpret_cast<const float4*>(&W2l[j0]);
    float bias2 = b2[0];
    #pragma unroll
    for (int i = 0; i < 8; ++i) {
        float h0 = relu_f(acc[i][0] + bv.x);
        float h1 = relu_f(acc[i][1] + bv.y);
        float h2 = relu_f(acc[i][2] + bv.z);
        float h3 = relu_f(acc[i][3] + bv.w);
        float p = h0 * w2.x + h1 * w2.y + h2 * w2.z + h3 * w2.w;
        #pragma unroll
        for (int m = 1; m < 32; m <<= 1) p += __shfl_xor(p, m, 64);
        if (jt == 0) {
            int row = row0 + r0 + i;
            if (row < E) out[row] = p + bias2;
        }
    }
}

extern "C" void kernel_launch(void* const* d_in, const int* in_sizes, int n_in,
                              void* d_out, int out_size, void* d_ws, size_t ws_size,
                              hipStream_t stream) {
    const int*   edge_type = (const int*)d_in[0];
    const int*   ab        = (const int*)d_in[1];
    const int*   bc        = (const int*)d_in[2];
    const int*   ac        = (const int*)d_in[3];
    const float* fe        = (const float*)d_in[4];
    const float* W1        = (const float*)d_in[5];
    const float* b1        = (const float*)d_in[6];
    const float* W2        = (const float*)d_in[7];
    const float* b2        = (const float*)d_in[8];
    const float* mW1       = (const float*)d_in[9];
    const float* mb1       = (const float*)d_in[10];
    const float* mW2       = (const float*)d_in[11];
    const float* mb2       = (const float*)d_in[12];

    const int E = in_sizes[0];
    const int T = in_sizes[1];
    float* out = (float*)d_out;

    // workspace layout
    char* p = (char*)d_ws;
    float* xa   = (float*)p;   p += (size_t)E * D * sizeof(float);
    float* xb   = (float*)p;   p += (size_t)E * D * sizeof(float);
    float* agg  = (float*)p;   p += (size_t)E * D * sizeof(float);
    int* cnt    = (int*)p;     p += (size_t)E * sizeof(int);
    int* lexcl  = (int*)p;     p += (size_t)E * sizeof(int);
    int* cursor = (int*)p;     p += (size_t)E * sizeof(int);
    int* bsums  = (int*)p;     p += 256 * sizeof(int);
    int2* seg   = (int2*)p;    p += (size_t)E * sizeof(int2);
    int2* tri   = (int2*)p;    p += (size_t)T * sizeof(int2);
    int* tte    = (int*)p;     p += (size_t)T * sizeof(int);

    const int nblkA = (E + 1023) / 1024;

    // CSR of triangles keyed by ac (reused by both layers)
    hipMemsetAsync(cnt, 0, (size_t)E * sizeof(int), stream);
    k_hist<<<(T + 255) / 256, 256, 0, stream>>>(ac, cnt, T);
    k_scanA<<<nblkA, 256, 0, stream>>>(cnt, lexcl, bsums, E);
    k_scanB<<<1, 256, 0, stream>>>(bsums, nblkA);
    k_scanC<<<(E + 255) / 256, 256, 0, stream>>>(lexcl, bsums, cnt, seg, cursor, E);
    k_permute<<<(T + 255) / 256, 256, 0, stream>>>(ab, bc, ac, edge_type, cursor, tri, tte, T);

    const int MSG_BLOCKS = 2048;
    const int nquad = MSG_BLOCKS * 256 / 64;   // one wave per 4 edges
    // layer 1 (x == fe[et], read straight from LDS-staged fact_emb)
    k_msg1<<<MSG_BLOCKS, 256, 0, stream>>>(seg, tte, fe, agg, E, nquad);
    k_linear<<<(E + 63) / 64, 256, 0, stream>>>(agg, W1, b1, xb, E);
    // layer 2
    k_msg4<<<MSG_BLOCKS, 256, 0, stream>>>(seg, tri, xb, agg, E, nquad);
    k_linear<<<(E + 63) / 64, 256, 0, stream>>>(agg, W2, b2, xa, E);

    k_mlp<<<(E + 127) / 128, 512, 0, stream>>>(xa, edge_type, fe, mW1, mb1, mW2, mb2, out, E);
}

// Round 11
// 198.960 us; speedup vs baseline: 5.0247x; 1.0775x over previous
//
#include <hip/hip_runtime.h>

#define D 64

__device__ __forceinline__ float relu_f(float v) { return v > 0.f ? v : 0.f; }

// ---------------- CSR build: histogram + scan + permute ----------------

__global__ void k_hist(const int* __restrict__ ac, int* __restrict__ cnt, int T) {
    int t = blockIdx.x * blockDim.x + threadIdx.x;
    if (t < T) atomicAdd(&cnt[ac[t]], 1);
}

__global__ __launch_bounds__(256) void k_scanA(const int* __restrict__ cnt,
        int* __restrict__ localExcl, int* __restrict__ blockSums, int E) {
    __shared__ int ls[256];
    const int tid = threadIdx.x;
    int base = blockIdx.x * 1024 + tid * 4;
    int a0 = 0, a1 = 0, a2 = 0, a3 = 0;
    if (base + 3 < E) {
        int4 v = *reinterpret_cast<const int4*>(cnt + base);
        a0 = v.x; a1 = v.y; a2 = v.z; a3 = v.w;
    } else {
        if (base + 0 < E) a0 = cnt[base + 0];
        if (base + 1 < E) a1 = cnt[base + 1];
        if (base + 2 < E) a2 = cnt[base + 2];
        if (base + 3 < E) a3 = cnt[base + 3];
    }
    int tsum = a0 + a1 + a2 + a3;
    ls[tid] = tsum;
    __syncthreads();
    for (int off = 1; off < 256; off <<= 1) {
        int v = (tid >= off) ? ls[tid - off] : 0;
        __syncthreads();
        ls[tid] += v;
        __syncthreads();
    }
    int excl = ls[tid] - tsum;
    if (tid == 255) blockSums[blockIdx.x] = ls[255];
    if (base + 3 < E) {
        int4 o = make_int4(excl, excl + a0, excl + a0 + a1, excl + a0 + a1 + a2);
        *reinterpret_cast<int4*>(localExcl + base) = o;
    } else {
        int run = excl;
        if (base + 0 < E) { localExcl[base + 0] = run; run += a0; }
        if (base + 1 < E) { localExcl[base + 1] = run; run += a1; }
        if (base + 2 < E) { localExcl[base + 2] = run; run += a2; }
        if (base + 3 < E) { localExcl[base + 3] = run; }
    }
}

// scanC with integrated scan of blockSums (nblk <= 256)
__global__ __launch_bounds__(256) void k_scanC(const int* __restrict__ localExcl,
        const int* __restrict__ blockSums, const int* __restrict__ cnt,
        int2* __restrict__ seg, int* __restrict__ cursor, int E, int nblk) {
    __shared__ int ls[256];
    const int tid = threadIdx.x;
    int v = (tid < nblk) ? blockSums[tid] : 0;
    ls[tid] = v;
    __syncthreads();
    for (int off = 1; off < 256; off <<= 1) {
        int w = (tid >= off) ? ls[tid - off] : 0;
        __syncthreads();
        ls[tid] += w;
        __syncthreads();
    }
    int excl = ls[tid] - v;     // exclusive prefix of blockSums
    __syncthreads();
    ls[tid] = excl;
    __syncthreads();
    int i = blockIdx.x * blockDim.x + tid;
    if (i < E) {
        int s = localExcl[i] + ls[i >> 10];
        seg[i] = make_int2(s, cnt[i]);
        cursor[i] = s;
    }
}

// tri[pos] = (ab, bc); pid[pos] = et[ab]*nrel + et[bc]
__global__ void k_permute(const int* __restrict__ ab, const int* __restrict__ bc,
                          const int* __restrict__ ac, const int* __restrict__ et,
                          int* __restrict__ cursor, int2* __restrict__ tri,
                          int* __restrict__ pid, int T, int nrel) {
    int t = blockIdx.x * blockDim.x + threadIdx.x;
    if (t >= T) return;
    int a = ab[t], b = bc[t];
    int pos = atomicAdd(&cursor[ac[t]], 1);
    tri[pos] = make_int2(a, b);
    pid[pos] = et[a] * nrel + et[b];
}

// ---------------- pair table: P[pa*nrel+pb][:] = (fe[pa] .* fe[pb]) @ W1 ----------------
#define FPAD 65
__global__ __launch_bounds__(256) void k_pair(const float* __restrict__ fe,
        const float* __restrict__ W1, float* __restrict__ P, int nrel) {
    __shared__ float Wl[64 * 64];
    __shared__ float fT[64 * FPAD];
    const int npair = nrel * nrel;
    const int tid = threadIdx.x;
    const int p0 = blockIdx.x * 64;

    for (int i = tid; i < 1024; i += 256)
        reinterpret_cast<float4*>(Wl)[i] = reinterpret_cast<const float4*>(W1)[i];

    for (int i = tid; i < 1024; i += 256) {
        int r = i >> 4, q = i & 15;
        int p = p0 + r;
        float4 v = make_float4(0.f, 0.f, 0.f, 0.f);
        if (p < npair) {
            int pa = p / nrel, pb = p - pa * nrel;
            float4 va = reinterpret_cast<const float4*>(fe + (size_t)pa * D)[q];
            float4 vb = reinterpret_cast<const float4*>(fe + (size_t)pb * D)[q];
            v = make_float4(va.x * vb.x, va.y * vb.y, va.z * vb.z, va.w * vb.w);
        }
        fT[(q * 4 + 0) * FPAD + r] = v.x;
        fT[(q * 4 + 1) * FPAD + r] = v.y;
        fT[(q * 4 + 2) * FPAD + r] = v.z;
        fT[(q * 4 + 3) * FPAD + r] = v.w;
    }
    __syncthreads();

    const int j0 = (tid & 15) * 4;
    const int r0 = (tid >> 4) * 4;
    float acc[4][4];
    #pragma unroll
    for (int i = 0; i < 4; ++i)
        #pragma unroll
        for (int j = 0; j < 4; ++j) acc[i][j] = 0.f;

    #pragma unroll 8
    for (int k = 0; k < 64; ++k) {
        float4 f = *reinterpret_cast<const float4*>(&fT[k * FPAD + r0]);
        float4 w = *reinterpret_cast<const float4*>(&Wl[k * 64 + j0]);
        float fa[4] = {f.x, f.y, f.z, f.w};
        float wa[4] = {w.x, w.y, w.z, w.w};
        #pragma unroll
        for (int i = 0; i < 4; ++i)
            #pragma unroll
            for (int j = 0; j < 4; ++j) acc[i][j] += fa[i] * wa[j];
    }

    #pragma unroll
    for (int i = 0; i < 4; ++i) {
        int p = p0 + r0 + i;
        if (p < npair) {
            float4 o = make_float4(acc[i][0], acc[i][1], acc[i][2], acc[i][3]);
            *reinterpret_cast<float4*>(P + (size_t)p * D + j0) = o;
        }
    }
}

// ---------------- layer-1: xb[e] = relu(sum_t P[pid_t] + b1) ----------------
// wave = 4 groups of 16 lanes; group owns one edge; lane sub holds 4 dims.
__global__ __launch_bounds__(256) void k_msg1b(const int2* __restrict__ seg,
        const int* __restrict__ pid, const float* __restrict__ P,
        const float* __restrict__ b1, float* __restrict__ xb, int E, int nquad) {
    const int tid = threadIdx.x;
    const int lane = tid & 63;
    const int sub = lane & 15;
    const int grp = lane >> 4;
    const float4* __restrict__ P4 = reinterpret_cast<const float4*>(P);
    const float4 bb = reinterpret_cast<const float4*>(b1)[sub];

    for (int quad = (blockIdx.x * blockDim.x + tid) >> 6; quad * 4 < E; quad += nquad) {
        const int e = quad * 4 + grp;
        int2 sc = make_int2(0, 0);
        if (e < E) sc = seg[e];
        const int s = sc.x, c = sc.y;
        float4 acc = make_float4(0.f, 0.f, 0.f, 0.f);
        int i = 0;
        for (; i + 3 < c; i += 4) {
            int q0 = pid[s + i + 0];
            int q1 = pid[s + i + 1];
            int q2 = pid[s + i + 2];
            int q3 = pid[s + i + 3];
            float4 v0 = P4[(size_t)q0 * 16 + sub];
            float4 v1 = P4[(size_t)q1 * 16 + sub];
            float4 v2 = P4[(size_t)q2 * 16 + sub];
            float4 v3 = P4[(size_t)q3 * 16 + sub];
            acc.x += v0.x + v1.x + v2.x + v3.x;
            acc.y += v0.y + v1.y + v2.y + v3.y;
            acc.z += v0.z + v1.z + v2.z + v3.z;
            acc.w += v0.w + v1.w + v2.w + v3.w;
        }
        for (; i < c; ++i) {
            float4 v = P4[(size_t)pid[s + i] * 16 + sub];
            acc.x += v.x; acc.y += v.y; acc.z += v.z; acc.w += v.w;
        }
        if (e < E) {
            float4 o;
            o.x = relu_f(acc.x + bb.x);
            o.y = relu_f(acc.y + bb.y);
            o.z = relu_f(acc.z + bb.z);
            o.w = relu_f(acc.w + bb.w);
            reinterpret_cast<float4*>(xb + (size_t)e * D)[sub] = o;
        }
    }
}

// ---------------- layer-2 message gather (unroll-4, batched loads) ----------------
__global__ __launch_bounds__(256) void k_msg4(const int2* __restrict__ seg,
        const int2* __restrict__ tri, const float* __restrict__ xin,
        float* __restrict__ agg, int E, int nquad) {
    const int tid = threadIdx.x;
    const int lane = tid & 63;
    const int sub = lane & 15;
    const int grp = lane >> 4;
    const float4* __restrict__ x4 = reinterpret_cast<const float4*>(xin);

    for (int quad = (blockIdx.x * blockDim.x + tid) >> 6; quad * 4 < E; quad += nquad) {
        const int e = quad * 4 + grp;
        int2 sc = make_int2(0, 0);
        if (e < E) sc = seg[e];
        const int s = sc.x, c = sc.y;
        float4 acc = make_float4(0.f, 0.f, 0.f, 0.f);
        int i = 0;
        for (; i + 3 < c; i += 4) {
            int2 p0 = tri[s + i + 0];
            int2 p1 = tri[s + i + 1];
            int2 p2 = tri[s + i + 2];
            int2 p3 = tri[s + i + 3];
            float4 va0 = x4[(size_t)p0.x * 16 + sub];
            float4 vb0 = x4[(size_t)p0.y * 16 + sub];
            float4 va1 = x4[(size_t)p1.x * 16 + sub];
            float4 vb1 = x4[(size_t)p1.y * 16 + sub];
            float4 va2 = x4[(size_t)p2.x * 16 + sub];
            float4 vb2 = x4[(size_t)p2.y * 16 + sub];
            float4 va3 = x4[(size_t)p3.x * 16 + sub];
            float4 vb3 = x4[(size_t)p3.y * 16 + sub];
            acc.x += va0.x * vb0.x; acc.y += va0.y * vb0.y;
            acc.z += va0.z * vb0.z; acc.w += va0.w * vb0.w;
            acc.x += va1.x * vb1.x; acc.y += va1.y * vb1.y;
            acc.z += va1.z * vb1.z; acc.w += va1.w * vb1.w;
            acc.x += va2.x * vb2.x; acc.y += va2.y * vb2.y;
            acc.z += va2.z * vb2.z; acc.w += va2.w * vb2.w;
            acc.x += va3.x * vb3.x; acc.y += va3.y * vb3.y;
            acc.z += va3.z * vb3.z; acc.w += va3.w * vb3.w;
        }
        for (; i < c; ++i) {
            int2 p = tri[s + i];
            float4 va = x4[(size_t)p.x * 16 + sub];
            float4 vb = x4[(size_t)p.y * 16 + sub];
            acc.x += va.x * vb.x;
            acc.y += va.y * vb.y;
            acc.z += va.z * vb.z;
            acc.w += va.w * vb.w;
        }
        if (e < E)
            reinterpret_cast<float4*>(agg + (size_t)e * D)[sub] = acc;
    }
}

// ---------------- 64x64 linear + relu (proven structure) ----------------
__global__ __launch_bounds__(256) void k_linear(const float* __restrict__ in,
        const float* __restrict__ W, const float* __restrict__ b,
        float* __restrict__ outx, int E) {
    __shared__ float Wl[64 * 64];
    __shared__ float fT[64 * FPAD];
    const int tid = threadIdx.x;
    const int row0 = blockIdx.x * 64;

    for (int i = tid; i < 1024; i += 256)
        reinterpret_cast<float4*>(Wl)[i] = reinterpret_cast<const float4*>(W)[i];

    for (int i = tid; i < 1024; i += 256) {
        int r = i >> 4, q = i & 15;
        float4 v = make_float4(0.f, 0.f, 0.f, 0.f);
        if (row0 + r < E)
            v = reinterpret_cast<const float4*>(in + (size_t)(row0 + r) * D)[q];
        fT[(q * 4 + 0) * FPAD + r] = v.x;
        fT[(q * 4 + 1) * FPAD + r] = v.y;
        fT[(q * 4 + 2) * FPAD + r] = v.z;
        fT[(q * 4 + 3) * FPAD + r] = v.w;
    }
    __syncthreads();

    const int j0 = (tid & 15) * 4;
    const int r0 = (tid >> 4) * 4;
    float acc[4][4];
    #pragma unroll
    for (int i = 0; i < 4; ++i)
        #pragma unroll
        for (int j = 0; j < 4; ++j) acc[i][j] = 0.f;

    #pragma unroll 8
    for (int k = 0; k < 64; ++k) {
        float4 f = *reinterpret_cast<const float4*>(&fT[k * FPAD + r0]);
        float4 w = *reinterpret_cast<const float4*>(&Wl[k * 64 + j0]);
        float fa[4] = {f.x, f.y, f.z, f.w};
        float wa[4] = {w.x, w.y, w.z, w.w};
        #pragma unroll
        for (int i = 0; i < 4; ++i)
            #pragma unroll
            for (int j = 0; j < 4; ++j) acc[i][j] += fa[i] * wa[j];
    }

    float4 bv = *reinterpret_cast<const float4*>(&b[j0]);
    float ba[4] = {bv.x, bv.y, bv.z, bv.w};
    #pragma unroll
    for (int i = 0; i < 4; ++i) {
        int row = row0 + r0 + i;
        if (row < E) {
            float4 o;
            o.x = relu_f(acc[i][0] + ba[0]);
            o.y = relu_f(acc[i][1] + ba[1]);
            o.z = relu_f(acc[i][2] + ba[2]);
            o.w = relu_f(acc[i][3] + ba[3]);
            *reinterpret_cast<float4*>(outx + (size_t)row * D + j0) = o;
        }
    }
}

// ---------------- final MLP (K-quartered + register double-buffered staging) ----------------
// 512 thr, 128 rows/block, 8x4 per thread; per quarter stage Wl[32][128]+fT[32][129];
// loads for quarter h+1 issued before compute(h) -> latency hides under FMA.
#define MPAD 129
__global__ __launch_bounds__(512) void k_mlp(const float* __restrict__ x,
        const int* __restrict__ et, const float* __restrict__ fe,
        const float* __restrict__ W1, const float* __restrict__ b1,
        const float* __restrict__ W2, const float* __restrict__ b2,
        float* __restrict__ out, int E) {
    __shared__ float Wl[32 * 128];      // 16 KB
    __shared__ float fT[32 * MPAD];     // 16.5 KB
    __shared__ float b1l[128];
    __shared__ float W2l[128];
    const int tid = threadIdx.x;
    const int row0 = blockIdx.x * 128;

    if (tid < 128) { b1l[tid] = b1[tid]; W2l[tid] = W2[tid]; }

    const float4* __restrict__ W1g = reinterpret_cast<const float4*>(W1);
    const float4* __restrict__ xg  = reinterpret_cast<const float4*>(x);
    const float4* __restrict__ feg = reinterpret_cast<const float4*>(fe);

    const int fr = tid >> 3;            // 0..63: feature row within half
    const int fq = tid & 7;             // 0..7: float4 col within quarter
    const int rowA = row0 + fr;
    const int rowB = row0 + fr + 64;
    const int etA = (rowA < E) ? et[rowA] : 0;
    const int etB = (rowB < E) ? et[rowB] : 0;

    float4 rW0, rW1, rF0, rF1;
    const float4 fzero = make_float4(0.f, 0.f, 0.f, 0.f);

    auto LDREG = [&](int h) {
        rW0 = W1g[h * 1024 + tid];
        rW1 = W1g[h * 1024 + tid + 512];
        int fcol = (h & 1) * 8 + fq;    // float4 col within 64-col source
        rF0 = fzero; rF1 = fzero;
        if (h < 2) {
            if (rowA < E) rF0 = xg[(size_t)rowA * 16 + fcol];
            if (rowB < E) rF1 = xg[(size_t)rowB * 16 + fcol];
        } else {
            if (rowA < E) rF0 = feg[(size_t)etA * 16 + fcol];
            if (rowB < E) rF1 = feg[(size_t)etB * 16 + fcol];
        }
    };
    auto STLDS = [&]() {
        reinterpret_cast<float4*>(Wl)[tid] = rW0;
        reinterpret_cast<float4*>(Wl)[tid + 512] = rW1;
        int kb = fq * 4;
        fT[(kb + 0) * MPAD + fr] = rF0.x;
        fT[(kb + 1) * MPAD + fr] = rF0.y;
        fT[(kb + 2) * MPAD + fr] = rF0.z;
        fT[(kb + 3) * MPAD + fr] = rF0.w;
        fT[(kb + 0) * MPAD + fr + 64] = rF1.x;
        fT[(kb + 1) * MPAD + fr + 64] = rF1.y;
        fT[(kb + 2) * MPAD + fr + 64] = rF1.z;
        fT[(kb + 3) * MPAD + fr + 64] = rF1.w;
    };

    const int jt = tid & 31;
    const int j0 = jt * 4;
    const int r0 = (tid >> 5) * 8;
    float acc[8][4];
    #pragma unroll
    for (int i = 0; i < 8; ++i)
        #pragma unroll
        for (int j = 0; j < 4; ++j) acc[i][j] = 0.f;

    LDREG(0);
    for (int h = 0; h < 4; ++h) {
        __syncthreads();                // previous quarter's readers done
        STLDS();
        __syncthreads();                // staging visible
        if (h < 3) LDREG(h + 1);        // issue next quarter's loads; hide under FMA

        #pragma unroll 4
        for (int k = 0; k < 32; ++k) {
            float4 fA = *reinterpret_cast<const float4*>(&fT[k * MPAD + r0]);
            float4 fB = *reinterpret_cast<const float4*>(&fT[k * MPAD + r0 + 4]);
            float4 w = *reinterpret_cast<const float4*>(&Wl[k * 128 + j0]);
            float fa[8] = {fA.x, fA.y, fA.z, fA.w, fB.x, fB.y, fB.z, fB.w};
            float wa[4] = {w.x, w.y, w.z, w.w};
            #pragma unroll
            for (int i = 0; i < 8; ++i)
                #pragma unroll
                for (int j = 0; j < 4; ++j) acc[i][j] += fa[i] * wa[j];
        }
    }

    float4 bv = *reinterpret_cast<const float4*>(&b1l[j0]);
    float4 w2 = *reinterpret_cast<const float4*>(&W2l[j0]);
    float bias2 = b2[0];
    #pragma unroll
    for (int i = 0; i < 8; ++i) {
        float h0 = relu_f(acc[i][0] + bv.x);
        float h1 = relu_f(acc[i][1] + bv.y);
        float h2 = relu_f(acc[i][2] + bv.z);
        float h3 = relu_f(acc[i][3] + bv.w);
        float p = h0 * w2.x + h1 * w2.y + h2 * w2.z + h3 * w2.w;
        #pragma unroll
        for (int m = 1; m < 32; m <<= 1) p += __shfl_xor(p, m, 64);
        if (jt == 0) {
            int row = row0 + r0 + i;
            if (row < E) out[row] = p + bias2;
        }
    }
}

extern "C" void kernel_launch(void* const* d_in, const int* in_sizes, int n_in,
                              void* d_out, int out_size, void* d_ws, size_t ws_size,
                              hipStream_t stream) {
    const int*   edge_type = (const int*)d_in[0];
    const int*   ab        = (const int*)d_in[1];
    const int*   bc        = (const int*)d_in[2];
    const int*   ac        = (const int*)d_in[3];
    const float* fe        = (const float*)d_in[4];
    const float* W1        = (const float*)d_in[5];
    const float* b1        = (const float*)d_in[6];
    const float* W2        = (const float*)d_in[7];
    const float* b2        = (const float*)d_in[8];
    const float* mW1       = (const float*)d_in[9];
    const float* mb1       = (const float*)d_in[10];
    const float* mW2       = (const float*)d_in[11];
    const float* mb2       = (const float*)d_in[12];

    const int E = in_sizes[0];
    const int T = in_sizes[1];
    const int nrel = in_sizes[4] / D;       // 102
    const int npair = nrel * nrel;
    float* out = (float*)d_out;

    // workspace layout
    char* p = (char*)d_ws;
    float* xa   = (float*)p;   p += (size_t)E * D * sizeof(float);
    float* xb   = (float*)p;   p += (size_t)E * D * sizeof(float);
    float* agg  = (float*)p;   p += (size_t)E * D * sizeof(float);
    float* P    = (float*)p;   p += (size_t)npair * D * sizeof(float);
    int* cnt    = (int*)p;     p += (size_t)E * sizeof(int);
    int* lexcl  = (int*)p;     p += (size_t)E * sizeof(int);
    int* cursor = (int*)p;     p += (size_t)E * sizeof(int);
    int* bsums  = (int*)p;     p += 256 * sizeof(int);
    int2* seg   = (int2*)p;    p += (size_t)E * sizeof(int2);
    int2* tri   = (int2*)p;    p += (size_t)T * sizeof(int2);
    int* pid    = (int*)p;     p += (size_t)T * sizeof(int);

    const int nblkA = (E + 1023) / 1024;

    // CSR of triangles keyed by ac (+ pair table build overlapped in-stream)
    hipMemsetAsync(cnt, 0, (size_t)E * sizeof(int), stream);
    k_hist<<<(T + 255) / 256, 256, 0, stream>>>(ac, cnt, T);
    k_pair<<<(npair + 63) / 64, 256, 0, stream>>>(fe, W1, P, nrel);
    k_scanA<<<nblkA, 256, 0, stream>>>(cnt, lexcl, bsums, E);
    k_scanC<<<(E + 255) / 256, 256, 0, stream>>>(lexcl, bsums, cnt, seg, cursor, E, nblkA);
    k_permute<<<(T + 255) / 256, 256, 0, stream>>>(ab, bc, ac, edge_type, cursor, tri, pid, T, nrel);

    const int MSG_BLOCKS = 2048;
    const int nquad = MSG_BLOCKS * 256 / 64;   // one wave per 4 edges
    // layer 1: algebraically fused (gather precomputed P rows, bias+relu inline)
    k_msg1b<<<MSG_BLOCKS, 256, 0, stream>>>(seg, pid, P, b1, xb, E, nquad);
    // layer 2
    k_msg4<<<MSG_BLOCKS, 256, 0, stream>>>(seg, tri, xb, agg, E, nquad);
    k_linear<<<(E + 63) / 64, 256, 0, stream>>>(agg, W2, b2, xa, E);

    k_mlp<<<(E + 127) / 128, 512, 0, stream>>>(xa, edge_type, fe, mW1, mb1, mW2, mb2, out, E);
}

// Round 12
// 182.930 us; speedup vs baseline: 5.4650x; 1.0876x over previous
//
#include <hip/hip_runtime.h>

#define D 64

__device__ __forceinline__ float relu_f(float v) { return v > 0.f ? v : 0.f; }

// ---------------- CSR build: histogram + scan + permute ----------------

__global__ void k_hist(const int* __restrict__ ac, int* __restrict__ cnt, int T) {
    int t = blockIdx.x * blockDim.x + threadIdx.x;
    if (t < T) atomicAdd(&cnt[ac[t]], 1);
}

__global__ __launch_bounds__(256) void k_scanA(const int* __restrict__ cnt,
        int* __restrict__ localExcl, int* __restrict__ blockSums, int E) {
    __shared__ int ls[256];
    const int tid = threadIdx.x;
    int base = blockIdx.x * 1024 + tid * 4;
    int a0 = 0, a1 = 0, a2 = 0, a3 = 0;
    if (base + 3 < E) {
        int4 v = *reinterpret_cast<const int4*>(cnt + base);
        a0 = v.x; a1 = v.y; a2 = v.z; a3 = v.w;
    } else {
        if (base + 0 < E) a0 = cnt[base + 0];
        if (base + 1 < E) a1 = cnt[base + 1];
        if (base + 2 < E) a2 = cnt[base + 2];
        if (base + 3 < E) a3 = cnt[base + 3];
    }
    int tsum = a0 + a1 + a2 + a3;
    ls[tid] = tsum;
    __syncthreads();
    for (int off = 1; off < 256; off <<= 1) {
        int v = (tid >= off) ? ls[tid - off] : 0;
        __syncthreads();
        ls[tid] += v;
        __syncthreads();
    }
    int excl = ls[tid] - tsum;
    if (tid == 255) blockSums[blockIdx.x] = ls[255];
    if (base + 3 < E) {
        int4 o = make_int4(excl, excl + a0, excl + a0 + a1, excl + a0 + a1 + a2);
        *reinterpret_cast<int4*>(localExcl + base) = o;
    } else {
        int run = excl;
        if (base + 0 < E) { localExcl[base + 0] = run; run += a0; }
        if (base + 1 < E) { localExcl[base + 1] = run; run += a1; }
        if (base + 2 < E) { localExcl[base + 2] = run; run += a2; }
        if (base + 3 < E) { localExcl[base + 3] = run; }
    }
}

// scanC with integrated scan of blockSums (nblk <= 256)
__global__ __launch_bounds__(256) void k_scanC(const int* __restrict__ localExcl,
        const int* __restrict__ blockSums, const int* __restrict__ cnt,
        int2* __restrict__ seg, int* __restrict__ cursor, int E, int nblk) {
    __shared__ int ls[256];
    const int tid = threadIdx.x;
    int v = (tid < nblk) ? blockSums[tid] : 0;
    ls[tid] = v;
    __syncthreads();
    for (int off = 1; off < 256; off <<= 1) {
        int w = (tid >= off) ? ls[tid - off] : 0;
        __syncthreads();
        ls[tid] += w;
        __syncthreads();
    }
    int excl = ls[tid] - v;     // exclusive prefix of blockSums
    __syncthreads();
    ls[tid] = excl;
    __syncthreads();
    int i = blockIdx.x * blockDim.x + tid;
    if (i < E) {
        int s = localExcl[i] + ls[i >> 10];
        seg[i] = make_int2(s, cnt[i]);
        cursor[i] = s;
    }
}

// tri[pos] = (ab, bc); pid[pos] = et[ab]*nrel + et[bc]
__global__ void k_permute(const int* __restrict__ ab, const int* __restrict__ bc,
                          const int* __restrict__ ac, const int* __restrict__ et,
                          int* __restrict__ cursor, int2* __restrict__ tri,
                          int* __restrict__ pid, int T, int nrel) {
    int t = blockIdx.x * blockDim.x + threadIdx.x;
    if (t >= T) return;
    int a = ab[t], b = bc[t];
    int pos = atomicAdd(&cursor[ac[t]], 1);
    tri[pos] = make_int2(a, b);
    pid[pos] = et[a] * nrel + et[b];
}

// ---------------- pair table: P[pa*nrel+pb][:] = (fe[pa] .* fe[pb]) @ W1 ----------------
#define FPAD 65
__global__ __launch_bounds__(256) void k_pair(const float* __restrict__ fe,
        const float* __restrict__ W1, float* __restrict__ P, int nrel) {
    __shared__ float Wl[64 * 64];
    __shared__ float fT[64 * FPAD];
    const int npair = nrel * nrel;
    const int tid = threadIdx.x;
    const int p0 = blockIdx.x * 64;

    for (int i = tid; i < 1024; i += 256)
        reinterpret_cast<float4*>(Wl)[i] = reinterpret_cast<const float4*>(W1)[i];

    for (int i = tid; i < 1024; i += 256) {
        int r = i >> 4, q = i & 15;
        int p = p0 + r;
        float4 v = make_float4(0.f, 0.f, 0.f, 0.f);
        if (p < npair) {
            int pa = p / nrel, pb = p - pa * nrel;
            float4 va = reinterpret_cast<const float4*>(fe + (size_t)pa * D)[q];
            float4 vb = reinterpret_cast<const float4*>(fe + (size_t)pb * D)[q];
            v = make_float4(va.x * vb.x, va.y * vb.y, va.z * vb.z, va.w * vb.w);
        }
        fT[(q * 4 + 0) * FPAD + r] = v.x;
        fT[(q * 4 + 1) * FPAD + r] = v.y;
        fT[(q * 4 + 2) * FPAD + r] = v.z;
        fT[(q * 4 + 3) * FPAD + r] = v.w;
    }
    __syncthreads();

    const int j0 = (tid & 15) * 4;
    const int r0 = (tid >> 4) * 4;
    float acc[4][4];
    #pragma unroll
    for (int i = 0; i < 4; ++i)
        #pragma unroll
        for (int j = 0; j < 4; ++j) acc[i][j] = 0.f;

    #pragma unroll 8
    for (int k = 0; k < 64; ++k) {
        float4 f = *reinterpret_cast<const float4*>(&fT[k * FPAD + r0]);
        float4 w = *reinterpret_cast<const float4*>(&Wl[k * 64 + j0]);
        float fa[4] = {f.x, f.y, f.z, f.w};
        float wa[4] = {w.x, w.y, w.z, w.w};
        #pragma unroll
        for (int i = 0; i < 4; ++i)
            #pragma unroll
            for (int j = 0; j < 4; ++j) acc[i][j] += fa[i] * wa[j];
    }

    #pragma unroll
    for (int i = 0; i < 4; ++i) {
        int p = p0 + r0 + i;
        if (p < npair) {
            float4 o = make_float4(acc[i][0], acc[i][1], acc[i][2], acc[i][3]);
            *reinterpret_cast<float4*>(P + (size_t)p * D + j0) = o;
        }
    }
}

// ---------------- Q table: Q[t][j] = sum_k fe[t][k]*mW1[64+k][j] + mb1[j] ----------------
__global__ __launch_bounds__(128) void k_qtab(const float* __restrict__ fe,
        const float* __restrict__ mW1, const float* __restrict__ mb1,
        float* __restrict__ Q) {
    __shared__ float fl[64];
    const int t = blockIdx.x;
    const int j = threadIdx.x;
    if (j < 64) fl[j] = fe[(size_t)t * D + j];
    __syncthreads();
    float s = mb1[j];
    #pragma unroll 16
    for (int k = 0; k < 64; ++k)
        s += fl[k] * mW1[(size_t)(64 + k) * 128 + j];
    Q[(size_t)t * 128 + j] = s;
}

// ---------------- layer-1: xb[e] = relu(sum_t P[pid_t] + b1) ----------------
__global__ __launch_bounds__(256) void k_msg1b(const int2* __restrict__ seg,
        const int* __restrict__ pid, const float* __restrict__ P,
        const float* __restrict__ b1, float* __restrict__ xb, int E, int nquad) {
    const int tid = threadIdx.x;
    const int lane = tid & 63;
    const int sub = lane & 15;
    const int grp = lane >> 4;
    const float4* __restrict__ P4 = reinterpret_cast<const float4*>(P);
    const float4 bb = reinterpret_cast<const float4*>(b1)[sub];

    for (int quad = (blockIdx.x * blockDim.x + tid) >> 6; quad * 4 < E; quad += nquad) {
        const int e = quad * 4 + grp;
        int2 sc = make_int2(0, 0);
        if (e < E) sc = seg[e];
        const int s = sc.x, c = sc.y;
        float4 acc = make_float4(0.f, 0.f, 0.f, 0.f);
        int i = 0;
        for (; i + 3 < c; i += 4) {
            int q0 = pid[s + i + 0];
            int q1 = pid[s + i + 1];
            int q2 = pid[s + i + 2];
            int q3 = pid[s + i + 3];
            float4 v0 = P4[(size_t)q0 * 16 + sub];
            float4 v1 = P4[(size_t)q1 * 16 + sub];
            float4 v2 = P4[(size_t)q2 * 16 + sub];
            float4 v3 = P4[(size_t)q3 * 16 + sub];
            acc.x += v0.x + v1.x + v2.x + v3.x;
            acc.y += v0.y + v1.y + v2.y + v3.y;
            acc.z += v0.z + v1.z + v2.z + v3.z;
            acc.w += v0.w + v1.w + v2.w + v3.w;
        }
        for (; i < c; ++i) {
            float4 v = P4[(size_t)pid[s + i] * 16 + sub];
            acc.x += v.x; acc.y += v.y; acc.z += v.z; acc.w += v.w;
        }
        if (e < E) {
            float4 o;
            o.x = relu_f(acc.x + bb.x);
            o.y = relu_f(acc.y + bb.y);
            o.z = relu_f(acc.z + bb.z);
            o.w = relu_f(acc.w + bb.w);
            reinterpret_cast<float4*>(xb + (size_t)e * D)[sub] = o;
        }
    }
}

// ---------------- layer-2 message gather (unroll-4, batched loads) ----------------
__global__ __launch_bounds__(256) void k_msg4(const int2* __restrict__ seg,
        const int2* __restrict__ tri, const float* __restrict__ xin,
        float* __restrict__ agg, int E, int nquad) {
    const int tid = threadIdx.x;
    const int lane = tid & 63;
    const int sub = lane & 15;
    const int grp = lane >> 4;
    const float4* __restrict__ x4 = reinterpret_cast<const float4*>(xin);

    for (int quad = (blockIdx.x * blockDim.x + tid) >> 6; quad * 4 < E; quad += nquad) {
        const int e = quad * 4 + grp;
        int2 sc = make_int2(0, 0);
        if (e < E) sc = seg[e];
        const int s = sc.x, c = sc.y;
        float4 acc = make_float4(0.f, 0.f, 0.f, 0.f);
        int i = 0;
        for (; i + 3 < c; i += 4) {
            int2 p0 = tri[s + i + 0];
            int2 p1 = tri[s + i + 1];
            int2 p2 = tri[s + i + 2];
            int2 p3 = tri[s + i + 3];
            float4 va0 = x4[(size_t)p0.x * 16 + sub];
            float4 vb0 = x4[(size_t)p0.y * 16 + sub];
            float4 va1 = x4[(size_t)p1.x * 16 + sub];
            float4 vb1 = x4[(size_t)p1.y * 16 + sub];
            float4 va2 = x4[(size_t)p2.x * 16 + sub];
            float4 vb2 = x4[(size_t)p2.y * 16 + sub];
            float4 va3 = x4[(size_t)p3.x * 16 + sub];
            float4 vb3 = x4[(size_t)p3.y * 16 + sub];
            acc.x += va0.x * vb0.x; acc.y += va0.y * vb0.y;
            acc.z += va0.z * vb0.z; acc.w += va0.w * vb0.w;
            acc.x += va1.x * vb1.x; acc.y += va1.y * vb1.y;
            acc.z += va1.z * vb1.z; acc.w += va1.w * vb1.w;
            acc.x += va2.x * vb2.x; acc.y += va2.y * vb2.y;
            acc.z += va2.z * vb2.z; acc.w += va2.w * vb2.w;
            acc.x += va3.x * vb3.x; acc.y += va3.y * vb3.y;
            acc.z += va3.z * vb3.z; acc.w += va3.w * vb3.w;
        }
        for (; i < c; ++i) {
            int2 p = tri[s + i];
            float4 va = x4[(size_t)p.x * 16 + sub];
            float4 vb = x4[(size_t)p.y * 16 + sub];
            acc.x += va.x * vb.x;
            acc.y += va.y * vb.y;
            acc.z += va.z * vb.z;
            acc.w += va.w * vb.w;
        }
        if (e < E)
            reinterpret_cast<float4*>(agg + (size_t)e * D)[sub] = acc;
    }
}

// ---------------- 64x64 linear + relu (proven structure) ----------------
__global__ __launch_bounds__(256) void k_linear(const float* __restrict__ in,
        const float* __restrict__ W, const float* __restrict__ b,
        float* __restrict__ outx, int E) {
    __shared__ float Wl[64 * 64];
    __shared__ float fT[64 * FPAD];
    const int tid = threadIdx.x;
    const int row0 = blockIdx.x * 64;

    for (int i = tid; i < 1024; i += 256)
        reinterpret_cast<float4*>(Wl)[i] = reinterpret_cast<const float4*>(W)[i];

    for (int i = tid; i < 1024; i += 256) {
        int r = i >> 4, q = i & 15;
        float4 v = make_float4(0.f, 0.f, 0.f, 0.f);
        if (row0 + r < E)
            v = reinterpret_cast<const float4*>(in + (size_t)(row0 + r) * D)[q];
        fT[(q * 4 + 0) * FPAD + r] = v.x;
        fT[(q * 4 + 1) * FPAD + r] = v.y;
        fT[(q * 4 + 2) * FPAD + r] = v.z;
        fT[(q * 4 + 3) * FPAD + r] = v.w;
    }
    __syncthreads();

    const int j0 = (tid & 15) * 4;
    const int r0 = (tid >> 4) * 4;
    float acc[4][4];
    #pragma unroll
    for (int i = 0; i < 4; ++i)
        #pragma unroll
        for (int j = 0; j < 4; ++j) acc[i][j] = 0.f;

    #pragma unroll 8
    for (int k = 0; k < 64; ++k) {
        float4 f = *reinterpret_cast<const float4*>(&fT[k * FPAD + r0]);
        float4 w = *reinterpret_cast<const float4*>(&Wl[k * 64 + j0]);
        float fa[4] = {f.x, f.y, f.z, f.w};
        float wa[4] = {w.x, w.y, w.z, w.w};
        #pragma unroll
        for (int i = 0; i < 4; ++i)
            #pragma unroll
            for (int j = 0; j < 4; ++j) acc[i][j] += fa[i] * wa[j];
    }

    float4 bv = *reinterpret_cast<const float4*>(&b[j0]);
    float ba[4] = {bv.x, bv.y, bv.z, bv.w};
    #pragma unroll
    for (int i = 0; i < 4; ++i) {
        int row = row0 + r0 + i;
        if (row < E) {
            float4 o;
            o.x = relu_f(acc[i][0] + ba[0]);
            o.y = relu_f(acc[i][1] + ba[1]);
            o.z = relu_f(acc[i][2] + ba[2]);
            o.w = relu_f(acc[i][3] + ba[3]);
            *reinterpret_cast<float4*>(outx + (size_t)row * D + j0) = o;
        }
    }
}

// ---------------- final MLP (K=64 via Q-table; 2 K-halves; round-10 staging) ----------------
// out[e] = relu(x[e] @ W1a + Q[et[e]]) @ W2 + b2   (Q = fe@W1b + b1 precomputed)
#define MPAD 129
__global__ __launch_bounds__(512) void k_mlp(const float* __restrict__ x,
        const int* __restrict__ et, const float* __restrict__ Q,
        const float* __restrict__ W1, const float* __restrict__ W2,
        const float* __restrict__ b2, float* __restrict__ out, int E) {
    __shared__ float Wl[32 * 128];      // 16 KB: one k-half of W1a
    __shared__ float fT[32 * MPAD];     // 16.5 KB
    __shared__ float W2l[128];
    const int tid = threadIdx.x;
    const int row0 = blockIdx.x * 128;

    if (tid < 128) W2l[tid] = W2[tid];

    const int jt = tid & 31;
    const int j0 = jt * 4;
    const int r0 = (tid >> 5) * 8;
    float acc[8][4];
    #pragma unroll
    for (int i = 0; i < 8; ++i)
        #pragma unroll
        for (int j = 0; j < 4; ++j) acc[i][j] = 0.f;

    for (int h = 0; h < 2; ++h) {
        __syncthreads();   // h=0: orders W2l; h=1: previous half's readers done
        // stage W1a k-half: rows h*32..h*32+31 (row-major contiguous)
        for (int i = tid; i < 1024; i += 512)
            reinterpret_cast<float4*>(Wl)[i] =
                reinterpret_cast<const float4*>(W1 + (size_t)h * 32 * 128)[i];
        // stage x columns h*32..h*32+31 transposed: 128 rows x 8 float4
        for (int i = tid; i < 1024; i += 512) {
            int r = i >> 3, q = i & 7;
            int row = row0 + r;
            float4 v = make_float4(0.f, 0.f, 0.f, 0.f);
            if (row < E)
                v = reinterpret_cast<const float4*>(x + (size_t)row * D)[h * 8 + q];
            int kb = q * 4;
            fT[(kb + 0) * MPAD + r] = v.x;
            fT[(kb + 1) * MPAD + r] = v.y;
            fT[(kb + 2) * MPAD + r] = v.z;
            fT[(kb + 3) * MPAD + r] = v.w;
        }
        __syncthreads();

        #pragma unroll 4
        for (int k = 0; k < 32; ++k) {
            float4 fA = *reinterpret_cast<const float4*>(&fT[k * MPAD + r0]);
            float4 fB = *reinterpret_cast<const float4*>(&fT[k * MPAD + r0 + 4]);
            float4 w = *reinterpret_cast<const float4*>(&Wl[k * 128 + j0]);
            float fa[8] = {fA.x, fA.y, fA.z, fA.w, fB.x, fB.y, fB.z, fB.w};
            float wa[4] = {w.x, w.y, w.z, w.w};
            #pragma unroll
            for (int i = 0; i < 8; ++i)
                #pragma unroll
                for (int j = 0; j < 4; ++j) acc[i][j] += fa[i] * wa[j];
        }
    }

    float4 w2 = *reinterpret_cast<const float4*>(&W2l[j0]);
    float bias2 = b2[0];
    #pragma unroll
    for (int i = 0; i < 8; ++i) {
        int row = row0 + r0 + i;
        float4 qv = make_float4(0.f, 0.f, 0.f, 0.f);
        if (row < E)
            qv = reinterpret_cast<const float4*>(Q + (size_t)et[row] * 128)[jt];
        float h0 = relu_f(acc[i][0] + qv.x);
        float h1 = relu_f(acc[i][1] + qv.y);
        float h2 = relu_f(acc[i][2] + qv.z);
        float h3 = relu_f(acc[i][3] + qv.w);
        float p = h0 * w2.x + h1 * w2.y + h2 * w2.z + h3 * w2.w;
        #pragma unroll
        for (int m = 1; m < 32; m <<= 1) p += __shfl_xor(p, m, 64);
        if (jt == 0 && row < E) out[row] = p + bias2;
    }
}

extern "C" void kernel_launch(void* const* d_in, const int* in_sizes, int n_in,
                              void* d_out, int out_size, void* d_ws, size_t ws_size,
                              hipStream_t stream) {
    const int*   edge_type = (const int*)d_in[0];
    const int*   ab        = (const int*)d_in[1];
    const int*   bc        = (const int*)d_in[2];
    const int*   ac        = (const int*)d_in[3];
    const float* fe        = (const float*)d_in[4];
    const float* W1        = (const float*)d_in[5];
    const float* b1        = (const float*)d_in[6];
    const float* W2        = (const float*)d_in[7];
    const float* b2        = (const float*)d_in[8];
    const float* mW1       = (const float*)d_in[9];
    const float* mb1       = (const float*)d_in[10];
    const float* mW2       = (const float*)d_in[11];
    const float* mb2       = (const float*)d_in[12];

    const int E = in_sizes[0];
    const int T = in_sizes[1];
    const int nrel = in_sizes[4] / D;       // 102
    const int npair = nrel * nrel;
    float* out = (float*)d_out;

    // workspace layout
    char* p = (char*)d_ws;
    float* xa   = (float*)p;   p += (size_t)E * D * sizeof(float);
    float* xb   = (float*)p;   p += (size_t)E * D * sizeof(float);
    float* agg  = (float*)p;   p += (size_t)E * D * sizeof(float);
    float* P    = (float*)p;   p += (size_t)npair * D * sizeof(float);
    float* Q    = (float*)p;   p += (size_t)nrel * 128 * sizeof(float);
    int* cnt    = (int*)p;     p += (size_t)E * sizeof(int);
    int* lexcl  = (int*)p;     p += (size_t)E * sizeof(int);
    int* cursor = (int*)p;     p += (size_t)E * sizeof(int);
    int* bsums  = (int*)p;     p += 256 * sizeof(int);
    int2* seg   = (int2*)p;    p += (size_t)E * sizeof(int2);
    int2* tri   = (int2*)p;    p += (size_t)T * sizeof(int2);
    int* pid    = (int*)p;     p += (size_t)T * sizeof(int);

    const int nblkA = (E + 1023) / 1024;

    // CSR of triangles keyed by ac (+ P/Q table builds overlapped in-stream)
    hipMemsetAsync(cnt, 0, (size_t)E * sizeof(int), stream);
    k_hist<<<(T + 255) / 256, 256, 0, stream>>>(ac, cnt, T);
    k_pair<<<(npair + 63) / 64, 256, 0, stream>>>(fe, W1, P, nrel);
    k_qtab<<<nrel, 128, 0, stream>>>(fe, mW1, mb1, Q);
    k_scanA<<<nblkA, 256, 0, stream>>>(cnt, lexcl, bsums, E);
    k_scanC<<<(E + 255) / 256, 256, 0, stream>>>(lexcl, bsums, cnt, seg, cursor, E, nblkA);
    k_permute<<<(T + 255) / 256, 256, 0, stream>>>(ab, bc, ac, edge_type, cursor, tri, pid, T, nrel);

    const int MSG_BLOCKS = 2048;
    const int nquad = MSG_BLOCKS * 256 / 64;   // one wave per 4 edges
    // layer 1: algebraically fused (gather precomputed P rows, bias+relu inline)
    k_msg1b<<<MSG_BLOCKS, 256, 0, stream>>>(seg, pid, P, b1, xb, E, nquad);
    // layer 2
    k_msg4<<<MSG_BLOCKS, 256, 0, stream>>>(seg, tri, xb, agg, E, nquad);
    k_linear<<<(E + 63) / 64, 256, 0, stream>>>(agg, W2, b2, xa, E);

    k_mlp<<<(E + 127) / 128, 512, 0, stream>>>(xa, edge_type, Q, mW1, mW2, mb2, out, E);
}